// Round 12
// baseline (1102.284 us; speedup 1.0000x reference)
//
#include <hip/hip_runtime.h>
#include <stdint.h>

#define RTOT 32768   // B*N
#define CR   16384   // rows per chunk (2 chunks; per-row network => independent)
#define NPTS 8192
#define MPTS 4096
#define NCH 8        // m-chunks per row
#define CHM 512      // m per chunk

typedef float f4v __attribute__((ext_vector_type(4)));
typedef short s8v __attribute__((ext_vector_type(8)));

// round-to-nearest-even bf16, returned as f32 (bf16-valued float)
__device__ __forceinline__ float bq(float f) {
    union { float f; uint32_t i; } u; u.f = f;
    u.i = (u.i + 0x7FFFu + ((u.i >> 16) & 1u)) & 0xFFFF0000u;
    return u.f;
}
__device__ __forceinline__ unsigned short f2bfu(float f) {
    union { float f; uint32_t i; } u; u.f = f;
    return (unsigned short)((u.i + 0x7FFFu + ((u.i >> 16) & 1u)) >> 16);
}
__device__ __forceinline__ float bfu2f(unsigned short s) {
    union { uint32_t i; float f; } u; u.i = ((uint32_t)s) << 16;
    return u.f;
}

// ---------------------------------------------------------------------------
// Weight transpose + hi/lo bf16 split: W (K x N f32) -> Wth/Wtl (N x K bf16).
// ---------------------------------------------------------------------------
__global__ __launch_bounds__(256) void transpose_split_kernel(
    const float* __restrict__ W, unsigned short* __restrict__ Wth,
    unsigned short* __restrict__ Wtl, int K, int N) {
    int i = blockIdx.x * 256 + threadIdx.x;
    if (i < K * N) {
        int n = i / K;
        int k = i % K;
        float w = W[(size_t)k * N + n];
        unsigned short h = f2bfu(w);
        Wth[i] = h;
        Wtl[i] = f2bfu(w - bfu2f(h));
    }
}

// ---------------------------------------------------------------------------
// Time embedding — dual-pass (blockIdx.z: 0 = f32, 1 = Q/bf16-emulated).
// FP output stored as hi/lo bf16 (bit-identical to consumer-side split; R8).
// ---------------------------------------------------------------------------
__global__ __launch_bounds__(256) void te0_dual(
    const float* __restrict__ ts,
    const float* __restrict__ w1, const float* __restrict__ b1,
    float* __restrict__ e1, float* __restrict__ e1q) {
    const bool Qv = (blockIdx.z == 1);
    __shared__ float emb[128];
    const int b = blockIdx.y;
    const int j = blockIdx.x * 256 + threadIdx.x;
    float t = ts[b];
    if (threadIdx.x < 128) {
        int k = threadIdx.x & 63;
        float f = expf((float)k * -0.14619587892025688f);
        float a = t * f;
        float v = (threadIdx.x < 64) ? sinf(a) : cosf(a);
        emb[threadIdx.x] = Qv ? bq(v) : v;
    }
    __syncthreads();
    float acc = 0.f;
    #pragma unroll 8
    for (int k = 0; k < 128; k++) {
        float w = w1[(size_t)k * 512 + j];
        acc += emb[k] * (Qv ? bq(w) : w);
    }
    acc += b1[j];
    if (Qv) {
        float h = bq(acc);
        float sg = bq(1.f / (1.f + expf(-h)));
        e1q[b * 512 + j] = bq(h * sg);
    } else {
        e1[b * 512 + j] = acc / (1.f + expf(-acc));
    }
}

__global__ __launch_bounds__(256) void te1_dual(
    const float* __restrict__ e1, const float* __restrict__ e1q,
    const float* __restrict__ w2, const float* __restrict__ b2,
    unsigned short* __restrict__ tembh, unsigned short* __restrict__ tembl,
    unsigned short* __restrict__ tembq) {
    const bool Qv = (blockIdx.z == 1);
    __shared__ float es[512];
    const int b = blockIdx.y;
    const int j = blockIdx.x * 256 + threadIdx.x;
    const float* src = Qv ? e1q : e1;
    float v0 = src[b * 512 + threadIdx.x];
    float v1 = src[b * 512 + 256 + threadIdx.x];
    es[threadIdx.x] = Qv ? bq(v0) : v0;
    es[256 + threadIdx.x] = Qv ? bq(v1) : v1;
    __syncthreads();
    float acc = 0.f;
    #pragma unroll 8
    for (int k = 0; k < 512; k++) {
        float w = w2[(size_t)k * 512 + j];
        acc += es[k] * (Qv ? bq(w) : w);
    }
    acc += b2[j];
    if (Qv) {
        tembq[b * 512 + j] = f2bfu(acc);   // same bits as bq(acc)
    } else {
        unsigned short h = f2bfu(acc);     // same split the consumer staging did
        tembh[b * 512 + j] = h;
        tembl[b * 512 + j] = f2bfu(acc - bfu2f(h));
    }
}

// ---------------------------------------------------------------------------
// NN search: EXACT f64 argmin (unchanged — established correct).
// ---------------------------------------------------------------------------
__global__ __launch_bounds__(256) void nn_partial_kernel(
    const float* __restrict__ NP, const float* __restrict__ TP,
    double* __restrict__ pd, int* __restrict__ pi) {
    __shared__ float tx[CHM], ty[CHM], tz[CHM];
    __shared__ double t264[CHM];
    const int t = threadIdx.x;
    const int r = blockIdx.x * 256 + t;
    const int b = r >> 13;
    const int ch = blockIdx.y;
    const int m0 = ch * CHM;
    for (int i = t; i < CHM; i += 256) {
        const float* p = TP + ((size_t)b * MPTS + m0 + i) * 3;
        float x = p[0], y = p[1], z = p[2];
        tx[i] = x; ty[i] = y; tz[i] = z;
        t264[i] = (double)x * x + (double)y * y + (double)z * z;
    }
    __syncthreads();
    const float* q = NP + (size_t)r * 3;
    double nx = (double)q[0], ny = (double)q[1], nz = (double)q[2];
    double sn = nx * nx + ny * ny + nz * nz;
    double g1 = 1e300; int j1 = 0;
    for (int m = 0; m < CHM; m++) {
        double d = (sn + t264[m]) - 2.0 * (nx * tx[m] + ny * ty[m] + nz * tz[m]);
        if (d < g1) { g1 = d; j1 = m; }
    }
    size_t o = (size_t)r * NCH + ch;
    pd[o] = g1;
    pi[o] = m0 + j1;
}

__global__ __launch_bounds__(256) void nn_merge_kernel(
    const float* __restrict__ NP, const float* __restrict__ TP,
    const double* __restrict__ pd, const int* __restrict__ pi,
    float* __restrict__ X0) {
    const int r = blockIdx.x * 256 + threadIdx.x;
    double g1 = 1e300; int j1 = 0;
    #pragma unroll
    for (int c = 0; c < NCH; c++) {
        size_t o = (size_t)r * NCH + c;
        double d = pd[o]; int i = pi[o];
        if (d < g1) { g1 = d; j1 = i; }
    }
    const int b = r >> 13;
    const float* tp = TP + ((size_t)b * MPTS + j1) * 3;
    const float* q = NP + (size_t)r * 3;
    float* o = X0 + (size_t)r * 6;
    o[0] = q[0]; o[1] = q[1]; o[2] = q[2];
    o[3] = tp[0]; o[4] = tp[1]; o[5] = tp[2];
}

// ---------------------------------------------------------------------------
// Layer 0 (K=6 -> 128) + LN + SiLU — dual-pass. FP writes hi/lo bf16 (R8,
// bit-identical to f32-store + consumer-side split).
// ---------------------------------------------------------------------------
__global__ __launch_bounds__(256) void layer0_dual(
    const float* __restrict__ X0, const float* __restrict__ W0,
    const float* __restrict__ b0, const float* __restrict__ g0,
    const float* __restrict__ e0,
    unsigned short* __restrict__ OutQ,
    unsigned short* __restrict__ OutFh, unsigned short* __restrict__ OutFl) {
    const bool Qp = (blockIdx.y == 0);
    const int wave = threadIdx.x >> 6;
    const int lane = threadIdx.x & 63;
    const int r = blockIdx.x * 4 + wave;
    float xk[6];
    #pragma unroll
    for (int k = 0; k < 6; k++) {
        float v = X0[(size_t)r * 6 + k];
        xk[k] = Qp ? bq(v) : v;
    }
    const int j0 = lane, j1 = lane + 64;
    float y0 = 0.f, y1 = 0.f;
    #pragma unroll
    for (int k = 0; k < 6; k++) {
        float w0 = W0[k * 128 + j0], w1 = W0[k * 128 + j1];
        y0 += xk[k] * (Qp ? bq(w0) : w0);
        y1 += xk[k] * (Qp ? bq(w1) : w1);
    }
    y0 += b0[j0];
    y1 += b0[j1];
    if (Qp) { y0 = bq(y0); y1 = bq(y1); }
    float s = y0 + y1;
    #pragma unroll
    for (int m = 1; m < 64; m <<= 1) s += __shfl_xor(s, m, 64);
    float mean = s * (1.f / 128.f);
    if (Qp) {
        mean = bq(mean);
        float c0 = bq(y0 - mean), c1 = bq(y1 - mean);
        float q0 = bq(c0 * c0), q1 = bq(c1 * c1);
        float sv = q0 + q1;
        #pragma unroll
        for (int m = 1; m < 64; m <<= 1) sv += __shfl_xor(sv, m, 64);
        float var = bq(sv * (1.f / 128.f));
        float sd = bq(sqrtf(bq(var + 1e-5f)));
        float d0 = bq(c0 / sd), d1 = bq(c1 / sd);
        d0 = bq(bq(d0 * g0[j0]) + e0[j0]);
        d1 = bq(bq(d1 * g0[j1]) + e0[j1]);
        float s0 = bq(1.f / (1.f + expf(-d0)));
        float s1 = bq(1.f / (1.f + expf(-d1)));
        OutQ[(size_t)r * 128 + j0] = f2bfu(d0 * s0);
        OutQ[(size_t)r * 128 + j1] = f2bfu(d1 * s1);
    } else {
        float sq = y0 * y0 + y1 * y1;
        #pragma unroll
        for (int m = 1; m < 64; m <<= 1) sq += __shfl_xor(sq, m, 64);
        float var = sq * (1.f / 128.f) - mean * mean;
        float rstd = rsqrtf(var + 1e-5f);
        float n0 = (y0 - mean) * rstd * g0[j0] + e0[j0];
        float n1 = (y1 - mean) * rstd * g0[j1] + e0[j1];
        float v0 = n0 / (1.f + expf(-n0));
        float v1 = n1 / (1.f + expf(-n1));
        unsigned short h0 = f2bfu(v0), h1 = f2bfu(v1);
        OutFh[(size_t)r * 128 + j0] = h0;
        OutFl[(size_t)r * 128 + j0] = f2bfu(v0 - bfu2f(h0));
        OutFh[(size_t)r * 128 + j1] = h1;
        OutFl[(size_t)r * 128 + j1] = f2bfu(v1 - bfu2f(h1));
    }
}

// ---------------------------------------------------------------------------
// MFMA fused layer — R12: R11 + FP B-chunk CHK 2 -> 1.
// R11 hit the 128-VGPR cap with a MILD spill (WRITE_SIZE 49->63 MB,
// ~100 B/thread — epilogue-scale) and zero k-loop headroom. CHK=1 frees
// 16 VGPR of B-fragments (bh[1]+bl[1] = 16 regs, was 32): scheduler can
// stop spilling AND hoist the next group's 2 loads above the current 12
// MFMAs (~120 cyc cover x 2 waves/SIMD >= L2 latency). Bit-exact: each
// acc[rt][ct]'s MFMA sequence (k-order, bh/bl/al*bh term order) is
// untouched; only interleaving across INDEPENDENT accumulators changes.
// Q path unchanged (CHK=4). Everything else frozen from R11.
// Spill canary: WRITE_SIZE (target ~49 MB).
// ---------------------------------------------------------------------------
#define AP 72   // 64 k + 8 pad u16: 144-B rows, 16-B aligned

template <int NOUT, bool FP>
__device__ __forceinline__ void mfma_body(
    const unsigned short* __restrict__ A1a, const unsigned short* __restrict__ A1b, int K1,
    const unsigned short* __restrict__ A2a, const unsigned short* __restrict__ A2b, int K2, int shift,
    const unsigned short* __restrict__ Wth,
    const unsigned short* __restrict__ Wtl,
    const float* __restrict__ bias,
    const float* __restrict__ gamma,
    const float* __restrict__ beta,
    unsigned short* __restrict__ OutQ,
    unsigned short* __restrict__ OutFh, unsigned short* __restrict__ OutFl,
    float* __restrict__ OutF32, int K,
    unsigned short* AhB, unsigned short* AlB, float (*lnS)[16], float (*lnQ)[16]) {
    constexpr int BNW = NOUT / 4;
    constexpr int CT = BNW / 16;
    constexpr int CHK = FP ? 1 : 4;      // B-col tiles per load group

    const int tid = threadIdx.x;
    const int wave = tid >> 6;
    const int lane = tid & 63;
    const int q = lane >> 4;
    const int c = lane & 15;
    const int r0 = blockIdx.x * 64;
    const int trow = tid >> 2;           // 64 rows, 4 threads/row
    const int tcol = (tid & 3) << 4;     // 16 contiguous k per thread
    const int r = r0 + trow;

    f4v acc[4][CT];
    #pragma unroll
    for (int rt = 0; rt < 4; rt++)
        #pragma unroll
        for (int ct = 0; ct < CT; ct++)
            acc[rt][ct] = (f4v)0.f;

    // ---- A-tile register prefetch: 16 u16/thread per array (pure copy) ----
    s8v qa[2], qb[2];
    auto loadA = [&](int k0) {
        const int kk = k0 + tcol;
        const unsigned short *sa, *sb;
        size_t idx;
        if (k0 < K1) { sa = A1a; sb = A1b; idx = (size_t)r * K1 + kk; }
        else         { sa = A2a; sb = A2b; idx = (size_t)(r >> shift) * K2 + (kk - K1); }
        qa[0] = *(const s8v*)(sa + idx);
        qa[1] = *(const s8v*)(sa + idx + 8);
        if (FP) {
            qb[0] = *(const s8v*)(sb + idx);
            qb[1] = *(const s8v*)(sb + idx + 8);
        }
    };

    loadA(0);
    int cur = 0;
    for (int k0 = 0; k0 < K; k0 += 64) {
        unsigned short* Ah = AhB + cur * (64 * AP);
        unsigned short* Al = AlB + cur * (64 * AP);
        // ---- stage prefetched regs -> LDS[cur] (copy only, no conversion) ----
        *(s8v*)(&Ah[trow * AP + tcol]) = qa[0];
        *(s8v*)(&Ah[trow * AP + tcol + 8]) = qa[1];
        if (FP) {
            *(s8v*)(&Al[trow * AP + tcol]) = qb[0];
            *(s8v*)(&Al[trow * AP + tcol + 8]) = qb[1];
        }
        // issue next tile's A global load before the barrier
        if (k0 + 64 < K) loadA(k0 + 64);
        __syncthreads();
        // ---- MFMA over two 32-k halves (single barrier: dbuf) ----
        #pragma unroll
        for (int kh = 0; kh < 2; kh++) {
            const int kb = k0 + kh * 32;
            #pragma unroll
            for (int ctb = 0; ctb < CT; ctb += CHK) {
                s8v bh[CHK], bl[CHK];
                #pragma unroll
                for (int j = 0; j < CHK; j++) {
                    int col = wave * BNW + (ctb + j) * 16 + c;
                    bh[j] = *(const s8v*)(Wth + (size_t)col * K + kb + q * 8);
                    if (FP) bl[j] = *(const s8v*)(Wtl + (size_t)col * K + kb + q * 8);
                }
                #pragma unroll
                for (int rt = 0; rt < 4; rt++) {
                    s8v ah = *(const s8v*)(&Ah[(rt * 16 + c) * AP + kh * 32 + q * 8]);
                    if (FP) {
                        s8v al = *(const s8v*)(&Al[(rt * 16 + c) * AP + kh * 32 + q * 8]);
                        #pragma unroll
                        for (int j = 0; j < CHK; j++) {
                            acc[rt][ctb + j] = __builtin_amdgcn_mfma_f32_16x16x32_bf16(ah, bh[j], acc[rt][ctb + j], 0, 0, 0);
                            acc[rt][ctb + j] = __builtin_amdgcn_mfma_f32_16x16x32_bf16(ah, bl[j], acc[rt][ctb + j], 0, 0, 0);
                            acc[rt][ctb + j] = __builtin_amdgcn_mfma_f32_16x16x32_bf16(al, bh[j], acc[rt][ctb + j], 0, 0, 0);
                        }
                    } else {
                        #pragma unroll
                        for (int j = 0; j < CHK; j++)
                            acc[rt][ctb + j] = __builtin_amdgcn_mfma_f32_16x16x32_bf16(ah, bh[j], acc[rt][ctb + j], 0, 0, 0);
                    }
                }
            }
        }
        cur ^= 1;
    }
    __syncthreads();

    // ---- epilogue (unchanged math per pass; rt 0..3) ----
    float bcol[CT], gcol[CT], ecol[CT];
    #pragma unroll
    for (int ct = 0; ct < CT; ct++) {
        int col = wave * BNW + ct * 16 + c;
        bcol[ct] = bias[col];
        gcol[ct] = gamma[col];
        ecol[ct] = beta[col];
    }
    const float inv = 1.f / (float)NOUT;
    #pragma unroll
    for (int rt = 0; rt < 4; rt++) {
        if (FP) {
            float s[4] = {0.f, 0.f, 0.f, 0.f}, sq[4] = {0.f, 0.f, 0.f, 0.f};
            #pragma unroll
            for (int ct = 0; ct < CT; ct++)
                #pragma unroll
                for (int reg = 0; reg < 4; reg++) {
                    float v = acc[rt][ct][reg] + bcol[ct];
                    acc[rt][ct][reg] = v;
                    s[reg] += v;
                    sq[reg] += v * v;
                }
            #pragma unroll
            for (int m = 1; m < 16; m <<= 1)
                #pragma unroll
                for (int reg = 0; reg < 4; reg++) {
                    s[reg] += __shfl_xor(s[reg], m, 64);
                    sq[reg] += __shfl_xor(sq[reg], m, 64);
                }
            if (c == 0)
                #pragma unroll
                for (int reg = 0; reg < 4; reg++) {
                    lnS[wave][q * 4 + reg] = s[reg];
                    lnQ[wave][q * 4 + reg] = sq[reg];
                }
            __syncthreads();
            #pragma unroll
            for (int reg = 0; reg < 4; reg++) {
                int lr = q * 4 + reg;
                float S = lnS[0][lr] + lnS[1][lr] + lnS[2][lr] + lnS[3][lr];
                float SQ = lnQ[0][lr] + lnQ[1][lr] + lnQ[2][lr] + lnQ[3][lr];
                float mean = S * inv;
                float var = SQ * inv - mean * mean;
                float rstd = rsqrtf(var + 1e-5f);
                size_t rr = (size_t)(r0 + rt * 16 + lr);
                #pragma unroll
                for (int ct = 0; ct < CT; ct++) {
                    float y = (acc[rt][ct][reg] - mean) * rstd * gcol[ct] + ecol[ct];
                    float ys = y / (1.f + expf(-y));
                    size_t idx = rr * NOUT + wave * BNW + ct * 16 + c;
                    if (OutF32) {
                        OutF32[idx] = ys;
                    } else {
                        unsigned short h = f2bfu(ys);
                        OutFh[idx] = h;
                        OutFl[idx] = f2bfu(ys - bfu2f(h));
                    }
                }
            }
            __syncthreads();
        } else {
            float s[4] = {0.f, 0.f, 0.f, 0.f};
            #pragma unroll
            for (int ct = 0; ct < CT; ct++)
                #pragma unroll
                for (int reg = 0; reg < 4; reg++) {
                    float h = bq(acc[rt][ct][reg] + bcol[ct]);
                    acc[rt][ct][reg] = h;
                    s[reg] += h;
                }
            #pragma unroll
            for (int m = 1; m < 16; m <<= 1)
                #pragma unroll
                for (int reg = 0; reg < 4; reg++)
                    s[reg] += __shfl_xor(s[reg], m, 64);
            if (c == 0)
                #pragma unroll
                for (int reg = 0; reg < 4; reg++)
                    lnS[wave][q * 4 + reg] = s[reg];
            __syncthreads();
            float mean[4], sv[4] = {0.f, 0.f, 0.f, 0.f};
            #pragma unroll
            for (int reg = 0; reg < 4; reg++) {
                int lr = q * 4 + reg;
                mean[reg] = bq((lnS[0][lr] + lnS[1][lr] + lnS[2][lr] + lnS[3][lr]) * inv);
            }
            #pragma unroll
            for (int ct = 0; ct < CT; ct++)
                #pragma unroll
                for (int reg = 0; reg < 4; reg++) {
                    float cc = bq(acc[rt][ct][reg] - mean[reg]);
                    acc[rt][ct][reg] = cc;
                    sv[reg] += bq(cc * cc);
                }
            #pragma unroll
            for (int m = 1; m < 16; m <<= 1)
                #pragma unroll
                for (int reg = 0; reg < 4; reg++)
                    sv[reg] += __shfl_xor(sv[reg], m, 64);
            if (c == 0)
                #pragma unroll
                for (int reg = 0; reg < 4; reg++)
                    lnQ[wave][q * 4 + reg] = sv[reg];
            __syncthreads();
            #pragma unroll
            for (int reg = 0; reg < 4; reg++) {
                int lr = q * 4 + reg;
                float var = bq((lnQ[0][lr] + lnQ[1][lr] + lnQ[2][lr] + lnQ[3][lr]) * inv);
                float sd = bq(sqrtf(bq(var + 1e-5f)));
                size_t rr = (size_t)(r0 + rt * 16 + lr);
                #pragma unroll
                for (int ct = 0; ct < CT; ct++) {
                    float d = bq(acc[rt][ct][reg] / sd);
                    d = bq(bq(d * gcol[ct]) + ecol[ct]);
                    float sg = bq(1.f / (1.f + expf(-d)));
                    OutQ[rr * NOUT + wave * BNW + ct * 16 + c] = f2bfu(d * sg);
                }
            }
            __syncthreads();
        }
    }
}

template <int NOUT>
__global__ __launch_bounds__(256, 2) void mfma_dual(
    const unsigned short* __restrict__ A1q,
    const unsigned short* __restrict__ A1h, const unsigned short* __restrict__ A1l, int K1,
    const unsigned short* __restrict__ A2q,
    const unsigned short* __restrict__ A2h, const unsigned short* __restrict__ A2l, int K2, int shift,
    const unsigned short* __restrict__ Wth,
    const unsigned short* __restrict__ Wtl,
    const float* __restrict__ bias,
    const float* __restrict__ gamma,
    const float* __restrict__ beta,
    unsigned short* __restrict__ OutQ,
    unsigned short* __restrict__ OutFh, unsigned short* __restrict__ OutFl,
    float* __restrict__ OutF32, int K) {
    __shared__ unsigned short Ah[2][64 * AP];   // double-buffered, 64 rows
    __shared__ unsigned short Al[2][64 * AP];
    __shared__ float lnS[4][16];
    __shared__ float lnQ[4][16];
    if (blockIdx.y == 0)
        mfma_body<NOUT, false>(A1q, nullptr, K1, A2q, nullptr, K2, shift, Wth, Wtl,
                               bias, gamma, beta, OutQ, nullptr, nullptr, nullptr, K,
                               &Ah[0][0], &Al[0][0], lnS, lnQ);
    else
        mfma_body<NOUT, true>(A1h, A1l, K1, A2h, A2l, K2, shift, Wth, Wtl,
                              bias, gamma, beta, OutQ, OutFh, OutFl, OutF32, K,
                              &Ah[0][0], &Al[0][0], lnS, lnQ);
}

// ---------------------------------------------------------------------------
// Output projection — fused Q + f32 dot, blends 0.2/0.8 exactly as before.
// ---------------------------------------------------------------------------
__global__ __launch_bounds__(256) void outproj_fused(
    const unsigned short* __restrict__ Xq, const float* __restrict__ Xf,
    const float* __restrict__ W, const float* __restrict__ bO,
    float* __restrict__ Out) {
    const int wave = threadIdx.x >> 6;
    const int lane = threadIdx.x & 63;
    const int r = blockIdx.x * 4 + wave;
    float q0 = 0.f, q1 = 0.f, q2 = 0.f;
    float f0 = 0.f, f1 = 0.f, f2 = 0.f;
    #pragma unroll
    for (int i = 0; i < 4; i++) {
        int k = lane + i * 64;
        float xq = bfu2f(Xq[(size_t)r * 256 + k]);
        float xf = Xf[(size_t)r * 256 + k];
        float w0 = W[k * 3 + 0], w1 = W[k * 3 + 1], w2 = W[k * 3 + 2];
        q0 += xq * bq(w0); q1 += xq * bq(w1); q2 += xq * bq(w2);
        f0 += xf * w0;     f1 += xf * w1;     f2 += xf * w2;
    }
    #pragma unroll
    for (int m = 1; m < 64; m <<= 1) {
        q0 += __shfl_xor(q0, m, 64);
        q1 += __shfl_xor(q1, m, 64);
        q2 += __shfl_xor(q2, m, 64);
        f0 += __shfl_xor(f0, m, 64);
        f1 += __shfl_xor(f1, m, 64);
        f2 += __shfl_xor(f2, m, 64);
    }
    if (lane == 0) {
        float a0 = bq(q0 + bO[0]);
        float a1 = bq(q1 + bO[1]);
        float a2 = bq(q2 + bO[2]);
        Out[(size_t)r * 3 + 0] = 0.2f * (f0 + bO[0]) + 0.8f * a0;
        Out[(size_t)r * 3 + 1] = 0.2f * (f1 + bO[1]) + 0.8f * a1;
        Out[(size_t)r * 3 + 2] = 0.2f * (f2 + bO[2]) + 0.8f * a2;
    }
}

// ---------------------------------------------------------------------------
extern "C" void kernel_launch(void* const* d_in, const int* in_sizes, int n_in,
                              void* d_out, int out_size, void* d_ws, size_t ws_size,
                              hipStream_t stream) {
    (void)in_sizes; (void)n_in; (void)out_size; (void)ws_size;
    const float* noisy  = (const float*)d_in[0];
    const float* target = (const float*)d_in[1];
    const float* tsteps = (const float*)d_in[2];
    const float* te_w1  = (const float*)d_in[3];
    const float* te_b1  = (const float*)d_in[4];
    const float* te_w2  = (const float*)d_in[5];
    const float* te_b2  = (const float*)d_in[6];
    const float* enc_w0 = (const float*)d_in[7];
    const float* enc_b0 = (const float*)d_in[8];
    const float* enc_g0 = (const float*)d_in[9];
    const float* enc_e0 = (const float*)d_in[10];
    const float* enc_w1 = (const float*)d_in[11];
    const float* enc_b1 = (const float*)d_in[12];
    const float* enc_g1 = (const float*)d_in[13];
    const float* enc_e1 = (const float*)d_in[14];
    const float* enc_w2 = (const float*)d_in[15];
    const float* enc_b2 = (const float*)d_in[16];
    const float* enc_g2 = (const float*)d_in[17];
    const float* enc_e2 = (const float*)d_in[18];
    const float* mid_w  = (const float*)d_in[19];
    const float* mid_b  = (const float*)d_in[20];
    const float* mid_g  = (const float*)d_in[21];
    const float* mid_e  = (const float*)d_in[22];
    const float* dec_w0 = (const float*)d_in[23];
    const float* dec_b0 = (const float*)d_in[24];
    const float* dec_g0 = (const float*)d_in[25];
    const float* dec_e0 = (const float*)d_in[26];
    const float* dec_w1 = (const float*)d_in[27];
    const float* dec_b1 = (const float*)d_in[28];
    const float* dec_g1 = (const float*)d_in[29];
    const float* dec_e1 = (const float*)d_in[30];
    const float* out_w  = (const float*)d_in[31];
    const float* out_b  = (const float*)d_in[32];

    char* ws = (char*)d_ws;
    size_t off = 0;
    auto alloc = [&](size_t n) { char* p = ws + off; off += (n + 255) & ~(size_t)255; return p; };

    // transposed hi/lo bf16 weights (~5 MB)
    unsigned short* wt_enc1h = (unsigned short*)alloc((size_t)256 * 128 * 2);
    unsigned short* wt_enc1l = (unsigned short*)alloc((size_t)256 * 128 * 2);
    unsigned short* wt_enc2h = (unsigned short*)alloc((size_t)512 * 256 * 2);
    unsigned short* wt_enc2l = (unsigned short*)alloc((size_t)512 * 256 * 2);
    unsigned short* wt_midh  = (unsigned short*)alloc((size_t)512 * 1024 * 2);
    unsigned short* wt_midl  = (unsigned short*)alloc((size_t)512 * 1024 * 2);
    unsigned short* wt_dec0h = (unsigned short*)alloc((size_t)512 * 768 * 2);
    unsigned short* wt_dec0l = (unsigned short*)alloc((size_t)512 * 768 * 2);
    unsigned short* wt_dec1h = (unsigned short*)alloc((size_t)256 * 640 * 2);
    unsigned short* wt_dec1l = (unsigned short*)alloc((size_t)256 * 640 * 2);

    float* e1    = (float*)alloc((size_t)4 * 512 * 4);
    float* e1q   = (float*)alloc((size_t)4 * 512 * 4);
    unsigned short* tembh = (unsigned short*)alloc((size_t)4 * 512 * 2);
    unsigned short* tembl = (unsigned short*)alloc((size_t)4 * 512 * 2);
    unsigned short* tembq = (unsigned short*)alloc((size_t)4 * 512 * 2);
    float* x0    = (float*)alloc((size_t)RTOT * 6 * 4);

    // CHUNK-SIZED activations (2 chunks of CR=16384 rows).
    // Q: raw bf16; FP: hi/lo bf16 pairs (same bytes as f32); dec1 FP out f32.
    // Peak ~170 MB < 183 known-good.
    unsigned short* skip0q  = (unsigned short*)alloc((size_t)CR * 128 * 2);
    unsigned short* skip1q  = (unsigned short*)alloc((size_t)CR * 256 * 2);
    unsigned short* xAq     = (unsigned short*)alloc((size_t)CR * 512 * 2);
    unsigned short* xBq     = (unsigned short*)alloc((size_t)CR * 512 * 2);
    unsigned short* skip0fh = (unsigned short*)alloc((size_t)CR * 128 * 2);
    unsigned short* skip0fl = (unsigned short*)alloc((size_t)CR * 128 * 2);
    unsigned short* skip1fh = (unsigned short*)alloc((size_t)CR * 256 * 2);
    unsigned short* skip1fl = (unsigned short*)alloc((size_t)CR * 256 * 2);
    unsigned short* xAfh    = (unsigned short*)alloc((size_t)CR * 512 * 2);
    unsigned short* xAfl    = (unsigned short*)alloc((size_t)CR * 512 * 2);
    unsigned short* xBfh    = (unsigned short*)alloc((size_t)CR * 512 * 2);
    unsigned short* xBfl    = (unsigned short*)alloc((size_t)CR * 512 * 2);
    float* xBf32 = (float*)alloc((size_t)CR * 512 * 4);   // dec1 FP out (feeds outproj)

    const int NE = RTOT * NCH;
    double* pd = (double*)xBf32;        // NN scratch (3 MB) aliased onto xBf32;
    int*    pi = (int*)(pd + NE);       // consumed before dec1 ever writes it

    // weight transposes + hi/lo split
    transpose_split_kernel<<<(256 * 128 + 255) / 256, 256, 0, stream>>>(enc_w1, wt_enc1h, wt_enc1l, 128, 256);
    transpose_split_kernel<<<(512 * 256 + 255) / 256, 256, 0, stream>>>(enc_w2, wt_enc2h, wt_enc2l, 256, 512);
    transpose_split_kernel<<<(512 * 1024 + 255) / 256, 256, 0, stream>>>(mid_w, wt_midh, wt_midl, 1024, 512);
    transpose_split_kernel<<<(512 * 768 + 255) / 256, 256, 0, stream>>>(dec_w0, wt_dec0h, wt_dec0l, 768, 512);
    transpose_split_kernel<<<(256 * 640 + 255) / 256, 256, 0, stream>>>(dec_w1, wt_dec1h, wt_dec1l, 640, 256);

    // time embeddings — both precisions in one launch each (z = variant)
    te0_dual<<<dim3(2, 4, 2), 256, 0, stream>>>(tsteps, te_w1, te_b1, e1, e1q);
    te1_dual<<<dim3(2, 4, 2), 256, 0, stream>>>(e1, e1q, te_w2, te_b2, tembh, tembl, tembq);

    // nearest neighbor (exact f64 argmin) + input concat
    nn_partial_kernel<<<dim3(128, NCH), 256, 0, stream>>>(noisy, target, pd, pi);
    nn_merge_kernel<<<128, 256, 0, stream>>>(noisy, target, pd, pi, x0);

    // ---------- both passes concurrent (blockIdx.y), 2 row-chunks ----------
    for (int ch = 0; ch < 2; ch++) {
        const float* x0c = x0 + (size_t)ch * CR * 6;
        const size_t to = (size_t)ch * 2 * 512;   // temb offset: batches 2ch..2ch+1
        float* outc = (float*)d_out + (size_t)ch * CR * 3;

        layer0_dual<<<dim3(CR / 4, 2), 256, 0, stream>>>(
            x0c, enc_w0, enc_b0, enc_g0, enc_e0, skip0q, skip0fh, skip0fl);
        mfma_dual<256><<<dim3(CR / 64, 2), 256, 0, stream>>>(
            skip0q, skip0fh, skip0fl, 128, nullptr, nullptr, nullptr, 0, 0,
            wt_enc1h, wt_enc1l, enc_b1, enc_g1, enc_e1,
            skip1q, skip1fh, skip1fl, nullptr, 128);
        mfma_dual<512><<<dim3(CR / 64, 2), 256, 0, stream>>>(
            skip1q, skip1fh, skip1fl, 256, nullptr, nullptr, nullptr, 0, 0,
            wt_enc2h, wt_enc2l, enc_b2, enc_g2, enc_e2,
            xAq, xAfh, xAfl, nullptr, 256);
        mfma_dual<512><<<dim3(CR / 64, 2), 256, 0, stream>>>(
            xAq, xAfh, xAfl, 512, tembq + to, tembh + to, tembl + to, 512, 13,
            wt_midh, wt_midl, mid_b, mid_g, mid_e,
            xBq, xBfh, xBfl, nullptr, 1024);
        mfma_dual<512><<<dim3(CR / 64, 2), 256, 0, stream>>>(
            xBq, xBfh, xBfl, 512, skip1q, skip1fh, skip1fl, 256, 0,
            wt_dec0h, wt_dec0l, dec_b0, dec_g0, dec_e0,
            xAq, xAfh, xAfl, nullptr, 768);
        mfma_dual<256><<<dim3(CR / 64, 2), 256, 0, stream>>>(
            xAq, xAfh, xAfl, 512, skip0q, skip0fh, skip0fl, 128, 0,
            wt_dec1h, wt_dec1l, dec_b1, dec_g1, dec_e1,
            xBq, nullptr, nullptr, xBf32, 640);
        outproj_fused<<<CR / 4, 256, 0, stream>>>(xBq, xBf32, out_w, out_b, outc);
    }
}

// Round 14
// 1086.247 us; speedup vs baseline: 1.0148x; 1.0148x over previous
//
#include <hip/hip_runtime.h>
#include <stdint.h>

#define RTOT 32768   // B*N
#define CR   16384   // rows per chunk (2 chunks; per-row network => independent)
#define NPTS 8192
#define MPTS 4096
#define NCH 8        // m-chunks per row
#define CHM 512      // m per chunk

typedef float f4v __attribute__((ext_vector_type(4)));
typedef short s8v __attribute__((ext_vector_type(8)));

// round-to-nearest-even bf16, returned as f32 (bf16-valued float)
__device__ __forceinline__ float bq(float f) {
    union { float f; uint32_t i; } u; u.f = f;
    u.i = (u.i + 0x7FFFu + ((u.i >> 16) & 1u)) & 0xFFFF0000u;
    return u.f;
}
__device__ __forceinline__ unsigned short f2bfu(float f) {
    union { float f; uint32_t i; } u; u.f = f;
    return (unsigned short)((u.i + 0x7FFFu + ((u.i >> 16) & 1u)) >> 16);
}
__device__ __forceinline__ float bfu2f(unsigned short s) {
    union { uint32_t i; float f; } u; u.i = ((uint32_t)s) << 16;
    return u.f;
}

// ---------------------------------------------------------------------------
// Weight transpose + hi/lo bf16 split: W (K x N f32) -> Wth/Wtl (N x K bf16).
// ---------------------------------------------------------------------------
__global__ __launch_bounds__(256) void transpose_split_kernel(
    const float* __restrict__ W, unsigned short* __restrict__ Wth,
    unsigned short* __restrict__ Wtl, int K, int N) {
    int i = blockIdx.x * 256 + threadIdx.x;
    if (i < K * N) {
        int n = i / K;
        int k = i % K;
        float w = W[(size_t)k * N + n];
        unsigned short h = f2bfu(w);
        Wth[i] = h;
        Wtl[i] = f2bfu(w - bfu2f(h));
    }
}

// ---------------------------------------------------------------------------
// Time embedding — dual-pass (blockIdx.z: 0 = f32, 1 = Q/bf16-emulated).
// FP output stored as hi/lo bf16 (bit-identical to consumer-side split; R8).
// ---------------------------------------------------------------------------
__global__ __launch_bounds__(256) void te0_dual(
    const float* __restrict__ ts,
    const float* __restrict__ w1, const float* __restrict__ b1,
    float* __restrict__ e1, float* __restrict__ e1q) {
    const bool Qv = (blockIdx.z == 1);
    __shared__ float emb[128];
    const int b = blockIdx.y;
    const int j = blockIdx.x * 256 + threadIdx.x;
    float t = ts[b];
    if (threadIdx.x < 128) {
        int k = threadIdx.x & 63;
        float f = expf((float)k * -0.14619587892025688f);
        float a = t * f;
        float v = (threadIdx.x < 64) ? sinf(a) : cosf(a);
        emb[threadIdx.x] = Qv ? bq(v) : v;
    }
    __syncthreads();
    float acc = 0.f;
    #pragma unroll 8
    for (int k = 0; k < 128; k++) {
        float w = w1[(size_t)k * 512 + j];
        acc += emb[k] * (Qv ? bq(w) : w);
    }
    acc += b1[j];
    if (Qv) {
        float h = bq(acc);
        float sg = bq(1.f / (1.f + expf(-h)));
        e1q[b * 512 + j] = bq(h * sg);
    } else {
        e1[b * 512 + j] = acc / (1.f + expf(-acc));
    }
}

__global__ __launch_bounds__(256) void te1_dual(
    const float* __restrict__ e1, const float* __restrict__ e1q,
    const float* __restrict__ w2, const float* __restrict__ b2,
    unsigned short* __restrict__ tembh, unsigned short* __restrict__ tembl,
    unsigned short* __restrict__ tembq) {
    const bool Qv = (blockIdx.z == 1);
    __shared__ float es[512];
    const int b = blockIdx.y;
    const int j = blockIdx.x * 256 + threadIdx.x;
    const float* src = Qv ? e1q : e1;
    float v0 = src[b * 512 + threadIdx.x];
    float v1 = src[b * 512 + 256 + threadIdx.x];
    es[threadIdx.x] = Qv ? bq(v0) : v0;
    es[256 + threadIdx.x] = Qv ? bq(v1) : v1;
    __syncthreads();
    float acc = 0.f;
    #pragma unroll 8
    for (int k = 0; k < 512; k++) {
        float w = w2[(size_t)k * 512 + j];
        acc += es[k] * (Qv ? bq(w) : w);
    }
    acc += b2[j];
    if (Qv) {
        tembq[b * 512 + j] = f2bfu(acc);   // same bits as bq(acc)
    } else {
        unsigned short h = f2bfu(acc);     // same split the consumer staging did
        tembh[b * 512 + j] = h;
        tembl[b * 512 + j] = f2bfu(acc - bfu2f(h));
    }
}

// ---------------------------------------------------------------------------
// NN search: EXACT f64 argmin (unchanged — established correct).
// ---------------------------------------------------------------------------
__global__ __launch_bounds__(256) void nn_partial_kernel(
    const float* __restrict__ NP, const float* __restrict__ TP,
    double* __restrict__ pd, int* __restrict__ pi) {
    __shared__ float tx[CHM], ty[CHM], tz[CHM];
    __shared__ double t264[CHM];
    const int t = threadIdx.x;
    const int r = blockIdx.x * 256 + t;
    const int b = r >> 13;
    const int ch = blockIdx.y;
    const int m0 = ch * CHM;
    for (int i = t; i < CHM; i += 256) {
        const float* p = TP + ((size_t)b * MPTS + m0 + i) * 3;
        float x = p[0], y = p[1], z = p[2];
        tx[i] = x; ty[i] = y; tz[i] = z;
        t264[i] = (double)x * x + (double)y * y + (double)z * z;
    }
    __syncthreads();
    const float* q = NP + (size_t)r * 3;
    double nx = (double)q[0], ny = (double)q[1], nz = (double)q[2];
    double sn = nx * nx + ny * ny + nz * nz;
    double g1 = 1e300; int j1 = 0;
    for (int m = 0; m < CHM; m++) {
        double d = (sn + t264[m]) - 2.0 * (nx * tx[m] + ny * ty[m] + nz * tz[m]);
        if (d < g1) { g1 = d; j1 = m; }
    }
    size_t o = (size_t)r * NCH + ch;
    pd[o] = g1;
    pi[o] = m0 + j1;
}

__global__ __launch_bounds__(256) void nn_merge_kernel(
    const float* __restrict__ NP, const float* __restrict__ TP,
    const double* __restrict__ pd, const int* __restrict__ pi,
    float* __restrict__ X0) {
    const int r = blockIdx.x * 256 + threadIdx.x;
    double g1 = 1e300; int j1 = 0;
    #pragma unroll
    for (int c = 0; c < NCH; c++) {
        size_t o = (size_t)r * NCH + c;
        double d = pd[o]; int i = pi[o];
        if (d < g1) { g1 = d; j1 = i; }
    }
    const int b = r >> 13;
    const float* tp = TP + ((size_t)b * MPTS + j1) * 3;
    const float* q = NP + (size_t)r * 3;
    float* o = X0 + (size_t)r * 6;
    o[0] = q[0]; o[1] = q[1]; o[2] = q[2];
    o[3] = tp[0]; o[4] = tp[1]; o[5] = tp[2];
}

// ---------------------------------------------------------------------------
// Layer 0 (K=6 -> 128) + LN + SiLU — dual-pass. FP writes hi/lo bf16 (R8,
// bit-identical to f32-store + consumer-side split).
// ---------------------------------------------------------------------------
__global__ __launch_bounds__(256) void layer0_dual(
    const float* __restrict__ X0, const float* __restrict__ W0,
    const float* __restrict__ b0, const float* __restrict__ g0,
    const float* __restrict__ e0,
    unsigned short* __restrict__ OutQ,
    unsigned short* __restrict__ OutFh, unsigned short* __restrict__ OutFl) {
    const bool Qp = (blockIdx.y == 0);
    const int wave = threadIdx.x >> 6;
    const int lane = threadIdx.x & 63;
    const int r = blockIdx.x * 4 + wave;
    float xk[6];
    #pragma unroll
    for (int k = 0; k < 6; k++) {
        float v = X0[(size_t)r * 6 + k];
        xk[k] = Qp ? bq(v) : v;
    }
    const int j0 = lane, j1 = lane + 64;
    float y0 = 0.f, y1 = 0.f;
    #pragma unroll
    for (int k = 0; k < 6; k++) {
        float w0 = W0[k * 128 + j0], w1 = W0[k * 128 + j1];
        y0 += xk[k] * (Qp ? bq(w0) : w0);
        y1 += xk[k] * (Qp ? bq(w1) : w1);
    }
    y0 += b0[j0];
    y1 += b0[j1];
    if (Qp) { y0 = bq(y0); y1 = bq(y1); }
    float s = y0 + y1;
    #pragma unroll
    for (int m = 1; m < 64; m <<= 1) s += __shfl_xor(s, m, 64);
    float mean = s * (1.f / 128.f);
    if (Qp) {
        mean = bq(mean);
        float c0 = bq(y0 - mean), c1 = bq(y1 - mean);
        float q0 = bq(c0 * c0), q1 = bq(c1 * c1);
        float sv = q0 + q1;
        #pragma unroll
        for (int m = 1; m < 64; m <<= 1) sv += __shfl_xor(sv, m, 64);
        float var = bq(sv * (1.f / 128.f));
        float sd = bq(sqrtf(bq(var + 1e-5f)));
        float d0 = bq(c0 / sd), d1 = bq(c1 / sd);
        d0 = bq(bq(d0 * g0[j0]) + e0[j0]);
        d1 = bq(bq(d1 * g0[j1]) + e0[j1]);
        float s0 = bq(1.f / (1.f + expf(-d0)));
        float s1 = bq(1.f / (1.f + expf(-d1)));
        OutQ[(size_t)r * 128 + j0] = f2bfu(d0 * s0);
        OutQ[(size_t)r * 128 + j1] = f2bfu(d1 * s1);
    } else {
        float sq = y0 * y0 + y1 * y1;
        #pragma unroll
        for (int m = 1; m < 64; m <<= 1) sq += __shfl_xor(sq, m, 64);
        float var = sq * (1.f / 128.f) - mean * mean;
        float rstd = rsqrtf(var + 1e-5f);
        float n0 = (y0 - mean) * rstd * g0[j0] + e0[j0];
        float n1 = (y1 - mean) * rstd * g0[j1] + e0[j1];
        float v0 = n0 / (1.f + expf(-n0));
        float v1 = n1 / (1.f + expf(-n1));
        unsigned short h0 = f2bfu(v0), h1 = f2bfu(v1);
        OutFh[(size_t)r * 128 + j0] = h0;
        OutFl[(size_t)r * 128 + j0] = f2bfu(v0 - bfu2f(h0));
        OutFh[(size_t)r * 128 + j1] = h1;
        OutFl[(size_t)r * 128 + j1] = f2bfu(v1 - bfu2f(h1));
    }
}

// ---------------------------------------------------------------------------
// MFMA fused layer — R14 = R13 resubmit (R13 was an infra failure; kernel
// never ran). R11 base (CHK=2; R12's CHK=1 null, spill epilogue-structural
// and benign at ~60 MB) + s_setprio(1) around the MFMA cluster. Regime:
// 2 independent blocks/CU at different phases => per-SIMD wave role
// diversity (m191 regime, +4-7%), not m190's barrier-locked null regime.
// Zero numeric effect.
// ---------------------------------------------------------------------------
#define AP 72   // 64 k + 8 pad u16: 144-B rows, 16-B aligned

template <int NOUT, bool FP>
__device__ __forceinline__ void mfma_body(
    const unsigned short* __restrict__ A1a, const unsigned short* __restrict__ A1b, int K1,
    const unsigned short* __restrict__ A2a, const unsigned short* __restrict__ A2b, int K2, int shift,
    const unsigned short* __restrict__ Wth,
    const unsigned short* __restrict__ Wtl,
    const float* __restrict__ bias,
    const float* __restrict__ gamma,
    const float* __restrict__ beta,
    unsigned short* __restrict__ OutQ,
    unsigned short* __restrict__ OutFh, unsigned short* __restrict__ OutFl,
    float* __restrict__ OutF32, int K,
    unsigned short* AhB, unsigned short* AlB, float (*lnS)[16], float (*lnQ)[16]) {
    constexpr int BNW = NOUT / 4;
    constexpr int CT = BNW / 16;
    constexpr int CHK = FP ? 2 : 4;      // B-col tiles per load group

    const int tid = threadIdx.x;
    const int wave = tid >> 6;
    const int lane = tid & 63;
    const int q = lane >> 4;
    const int c = lane & 15;
    const int r0 = blockIdx.x * 64;
    const int trow = tid >> 2;           // 64 rows, 4 threads/row
    const int tcol = (tid & 3) << 4;     // 16 contiguous k per thread
    const int r = r0 + trow;

    f4v acc[4][CT];
    #pragma unroll
    for (int rt = 0; rt < 4; rt++)
        #pragma unroll
        for (int ct = 0; ct < CT; ct++)
            acc[rt][ct] = (f4v)0.f;

    // ---- A-tile register prefetch: 16 u16/thread per array (pure copy) ----
    s8v qa[2], qb[2];
    auto loadA = [&](int k0) {
        const int kk = k0 + tcol;
        const unsigned short *sa, *sb;
        size_t idx;
        if (k0 < K1) { sa = A1a; sb = A1b; idx = (size_t)r * K1 + kk; }
        else         { sa = A2a; sb = A2b; idx = (size_t)(r >> shift) * K2 + (kk - K1); }
        qa[0] = *(const s8v*)(sa + idx);
        qa[1] = *(const s8v*)(sa + idx + 8);
        if (FP) {
            qb[0] = *(const s8v*)(sb + idx);
            qb[1] = *(const s8v*)(sb + idx + 8);
        }
    };

    loadA(0);
    int cur = 0;
    for (int k0 = 0; k0 < K; k0 += 64) {
        unsigned short* Ah = AhB + cur * (64 * AP);
        unsigned short* Al = AlB + cur * (64 * AP);
        // ---- stage prefetched regs -> LDS[cur] (copy only, no conversion) ----
        *(s8v*)(&Ah[trow * AP + tcol]) = qa[0];
        *(s8v*)(&Ah[trow * AP + tcol + 8]) = qa[1];
        if (FP) {
            *(s8v*)(&Al[trow * AP + tcol]) = qb[0];
            *(s8v*)(&Al[trow * AP + tcol + 8]) = qb[1];
        }
        // issue next tile's A global load before the barrier
        if (k0 + 64 < K) loadA(k0 + 64);
        __syncthreads();
        // ---- MFMA over two 32-k halves (single barrier: dbuf) ----
        __builtin_amdgcn_s_setprio(1);
        #pragma unroll
        for (int kh = 0; kh < 2; kh++) {
            const int kb = k0 + kh * 32;
            #pragma unroll
            for (int ctb = 0; ctb < CT; ctb += CHK) {
                s8v bh[CHK], bl[CHK];
                #pragma unroll
                for (int j = 0; j < CHK; j++) {
                    int col = wave * BNW + (ctb + j) * 16 + c;
                    bh[j] = *(const s8v*)(Wth + (size_t)col * K + kb + q * 8);
                    if (FP) bl[j] = *(const s8v*)(Wtl + (size_t)col * K + kb + q * 8);
                }
                #pragma unroll
                for (int rt = 0; rt < 4; rt++) {
                    s8v ah = *(const s8v*)(&Ah[(rt * 16 + c) * AP + kh * 32 + q * 8]);
                    if (FP) {
                        s8v al = *(const s8v*)(&Al[(rt * 16 + c) * AP + kh * 32 + q * 8]);
                        #pragma unroll
                        for (int j = 0; j < CHK; j++) {
                            acc[rt][ctb + j] = __builtin_amdgcn_mfma_f32_16x16x32_bf16(ah, bh[j], acc[rt][ctb + j], 0, 0, 0);
                            acc[rt][ctb + j] = __builtin_amdgcn_mfma_f32_16x16x32_bf16(ah, bl[j], acc[rt][ctb + j], 0, 0, 0);
                            acc[rt][ctb + j] = __builtin_amdgcn_mfma_f32_16x16x32_bf16(al, bh[j], acc[rt][ctb + j], 0, 0, 0);
                        }
                    } else {
                        #pragma unroll
                        for (int j = 0; j < CHK; j++)
                            acc[rt][ctb + j] = __builtin_amdgcn_mfma_f32_16x16x32_bf16(ah, bh[j], acc[rt][ctb + j], 0, 0, 0);
                    }
                }
            }
        }
        __builtin_amdgcn_s_setprio(0);
        cur ^= 1;
    }
    __syncthreads();

    // ---- epilogue (unchanged math per pass; rt 0..3) ----
    float bcol[CT], gcol[CT], ecol[CT];
    #pragma unroll
    for (int ct = 0; ct < CT; ct++) {
        int col = wave * BNW + ct * 16 + c;
        bcol[ct] = bias[col];
        gcol[ct] = gamma[col];
        ecol[ct] = beta[col];
    }
    const float inv = 1.f / (float)NOUT;
    #pragma unroll
    for (int rt = 0; rt < 4; rt++) {
        if (FP) {
            float s[4] = {0.f, 0.f, 0.f, 0.f}, sq[4] = {0.f, 0.f, 0.f, 0.f};
            #pragma unroll
            for (int ct = 0; ct < CT; ct++)
                #pragma unroll
                for (int reg = 0; reg < 4; reg++) {
                    float v = acc[rt][ct][reg] + bcol[ct];
                    acc[rt][ct][reg] = v;
                    s[reg] += v;
                    sq[reg] += v * v;
                }
            #pragma unroll
            for (int m = 1; m < 16; m <<= 1)
                #pragma unroll
                for (int reg = 0; reg < 4; reg++) {
                    s[reg] += __shfl_xor(s[reg], m, 64);
                    sq[reg] += __shfl_xor(sq[reg], m, 64);
                }
            if (c == 0)
                #pragma unroll
                for (int reg = 0; reg < 4; reg++) {
                    lnS[wave][q * 4 + reg] = s[reg];
                    lnQ[wave][q * 4 + reg] = sq[reg];
                }
            __syncthreads();
            #pragma unroll
            for (int reg = 0; reg < 4; reg++) {
                int lr = q * 4 + reg;
                float S = lnS[0][lr] + lnS[1][lr] + lnS[2][lr] + lnS[3][lr];
                float SQ = lnQ[0][lr] + lnQ[1][lr] + lnQ[2][lr] + lnQ[3][lr];
                float mean = S * inv;
                float var = SQ * inv - mean * mean;
                float rstd = rsqrtf(var + 1e-5f);
                size_t rr = (size_t)(r0 + rt * 16 + lr);
                #pragma unroll
                for (int ct = 0; ct < CT; ct++) {
                    float y = (acc[rt][ct][reg] - mean) * rstd * gcol[ct] + ecol[ct];
                    float ys = y / (1.f + expf(-y));
                    size_t idx = rr * NOUT + wave * BNW + ct * 16 + c;
                    if (OutF32) {
                        OutF32[idx] = ys;
                    } else {
                        unsigned short h = f2bfu(ys);
                        OutFh[idx] = h;
                        OutFl[idx] = f2bfu(ys - bfu2f(h));
                    }
                }
            }
            __syncthreads();
        } else {
            float s[4] = {0.f, 0.f, 0.f, 0.f};
            #pragma unroll
            for (int ct = 0; ct < CT; ct++)
                #pragma unroll
                for (int reg = 0; reg < 4; reg++) {
                    float h = bq(acc[rt][ct][reg] + bcol[ct]);
                    acc[rt][ct][reg] = h;
                    s[reg] += h;
                }
            #pragma unroll
            for (int m = 1; m < 16; m <<= 1)
                #pragma unroll
                for (int reg = 0; reg < 4; reg++)
                    s[reg] += __shfl_xor(s[reg], m, 64);
            if (c == 0)
                #pragma unroll
                for (int reg = 0; reg < 4; reg++)
                    lnS[wave][q * 4 + reg] = s[reg];
            __syncthreads();
            float mean[4], sv[4] = {0.f, 0.f, 0.f, 0.f};
            #pragma unroll
            for (int reg = 0; reg < 4; reg++) {
                int lr = q * 4 + reg;
                mean[reg] = bq((lnS[0][lr] + lnS[1][lr] + lnS[2][lr] + lnS[3][lr]) * inv);
            }
            #pragma unroll
            for (int ct = 0; ct < CT; ct++)
                #pragma unroll
                for (int reg = 0; reg < 4; reg++) {
                    float cc = bq(acc[rt][ct][reg] - mean[reg]);
                    acc[rt][ct][reg] = cc;
                    sv[reg] += bq(cc * cc);
                }
            #pragma unroll
            for (int m = 1; m < 16; m <<= 1)
                #pragma unroll
                for (int reg = 0; reg < 4; reg++)
                    sv[reg] += __shfl_xor(sv[reg], m, 64);
            if (c == 0)
                #pragma unroll
                for (int reg = 0; reg < 4; reg++)
                    lnQ[wave][q * 4 + reg] = sv[reg];
            __syncthreads();
            #pragma unroll
            for (int reg = 0; reg < 4; reg++) {
                int lr = q * 4 + reg;
                float var = bq((lnQ[0][lr] + lnQ[1][lr] + lnQ[2][lr] + lnQ[3][lr]) * inv);
                float sd = bq(sqrtf(bq(var + 1e-5f)));
                size_t rr = (size_t)(r0 + rt * 16 + lr);
                #pragma unroll
                for (int ct = 0; ct < CT; ct++) {
                    float d = bq(acc[rt][ct][reg] / sd);
                    d = bq(bq(d * gcol[ct]) + ecol[ct]);
                    float sg = bq(1.f / (1.f + expf(-d)));
                    OutQ[rr * NOUT + wave * BNW + ct * 16 + c] = f2bfu(d * sg);
                }
            }
            __syncthreads();
        }
    }
}

template <int NOUT>
__global__ __launch_bounds__(256, 2) void mfma_dual(
    const unsigned short* __restrict__ A1q,
    const unsigned short* __restrict__ A1h, const unsigned short* __restrict__ A1l, int K1,
    const unsigned short* __restrict__ A2q,
    const unsigned short* __restrict__ A2h, const unsigned short* __restrict__ A2l, int K2, int shift,
    const unsigned short* __restrict__ Wth,
    const unsigned short* __restrict__ Wtl,
    const float* __restrict__ bias,
    const float* __restrict__ gamma,
    const float* __restrict__ beta,
    unsigned short* __restrict__ OutQ,
    unsigned short* __restrict__ OutFh, unsigned short* __restrict__ OutFl,
    float* __restrict__ OutF32, int K) {
    __shared__ unsigned short Ah[2][64 * AP];   // double-buffered, 64 rows
    __shared__ unsigned short Al[2][64 * AP];
    __shared__ float lnS[4][16];
    __shared__ float lnQ[4][16];
    if (blockIdx.y == 0)
        mfma_body<NOUT, false>(A1q, nullptr, K1, A2q, nullptr, K2, shift, Wth, Wtl,
                               bias, gamma, beta, OutQ, nullptr, nullptr, nullptr, K,
                               &Ah[0][0], &Al[0][0], lnS, lnQ);
    else
        mfma_body<NOUT, true>(A1h, A1l, K1, A2h, A2l, K2, shift, Wth, Wtl,
                              bias, gamma, beta, OutQ, OutFh, OutFl, OutF32, K,
                              &Ah[0][0], &Al[0][0], lnS, lnQ);
}

// ---------------------------------------------------------------------------
// Output projection — fused Q + f32 dot, blends 0.2/0.8 exactly as before.
// ---------------------------------------------------------------------------
__global__ __launch_bounds__(256) void outproj_fused(
    const unsigned short* __restrict__ Xq, const float* __restrict__ Xf,
    const float* __restrict__ W, const float* __restrict__ bO,
    float* __restrict__ Out) {
    const int wave = threadIdx.x >> 6;
    const int lane = threadIdx.x & 63;
    const int r = blockIdx.x * 4 + wave;
    float q0 = 0.f, q1 = 0.f, q2 = 0.f;
    float f0 = 0.f, f1 = 0.f, f2 = 0.f;
    #pragma unroll
    for (int i = 0; i < 4; i++) {
        int k = lane + i * 64;
        float xq = bfu2f(Xq[(size_t)r * 256 + k]);
        float xf = Xf[(size_t)r * 256 + k];
        float w0 = W[k * 3 + 0], w1 = W[k * 3 + 1], w2 = W[k * 3 + 2];
        q0 += xq * bq(w0); q1 += xq * bq(w1); q2 += xq * bq(w2);
        f0 += xf * w0;     f1 += xf * w1;     f2 += xf * w2;
    }
    #pragma unroll
    for (int m = 1; m < 64; m <<= 1) {
        q0 += __shfl_xor(q0, m, 64);
        q1 += __shfl_xor(q1, m, 64);
        q2 += __shfl_xor(q2, m, 64);
        f0 += __shfl_xor(f0, m, 64);
        f1 += __shfl_xor(f1, m, 64);
        f2 += __shfl_xor(f2, m, 64);
    }
    if (lane == 0) {
        float a0 = bq(q0 + bO[0]);
        float a1 = bq(q1 + bO[1]);
        float a2 = bq(q2 + bO[2]);
        Out[(size_t)r * 3 + 0] = 0.2f * (f0 + bO[0]) + 0.8f * a0;
        Out[(size_t)r * 3 + 1] = 0.2f * (f1 + bO[1]) + 0.8f * a1;
        Out[(size_t)r * 3 + 2] = 0.2f * (f2 + bO[2]) + 0.8f * a2;
    }
}

// ---------------------------------------------------------------------------
extern "C" void kernel_launch(void* const* d_in, const int* in_sizes, int n_in,
                              void* d_out, int out_size, void* d_ws, size_t ws_size,
                              hipStream_t stream) {
    (void)in_sizes; (void)n_in; (void)out_size; (void)ws_size;
    const float* noisy  = (const float*)d_in[0];
    const float* target = (const float*)d_in[1];
    const float* tsteps = (const float*)d_in[2];
    const float* te_w1  = (const float*)d_in[3];
    const float* te_b1  = (const float*)d_in[4];
    const float* te_w2  = (const float*)d_in[5];
    const float* te_b2  = (const float*)d_in[6];
    const float* enc_w0 = (const float*)d_in[7];
    const float* enc_b0 = (const float*)d_in[8];
    const float* enc_g0 = (const float*)d_in[9];
    const float* enc_e0 = (const float*)d_in[10];
    const float* enc_w1 = (const float*)d_in[11];
    const float* enc_b1 = (const float*)d_in[12];
    const float* enc_g1 = (const float*)d_in[13];
    const float* enc_e1 = (const float*)d_in[14];
    const float* enc_w2 = (const float*)d_in[15];
    const float* enc_b2 = (const float*)d_in[16];
    const float* enc_g2 = (const float*)d_in[17];
    const float* enc_e2 = (const float*)d_in[18];
    const float* mid_w  = (const float*)d_in[19];
    const float* mid_b  = (const float*)d_in[20];
    const float* mid_g  = (const float*)d_in[21];
    const float* mid_e  = (const float*)d_in[22];
    const float* dec_w0 = (const float*)d_in[23];
    const float* dec_b0 = (const float*)d_in[24];
    const float* dec_g0 = (const float*)d_in[25];
    const float* dec_e0 = (const float*)d_in[26];
    const float* dec_w1 = (const float*)d_in[27];
    const float* dec_b1 = (const float*)d_in[28];
    const float* dec_g1 = (const float*)d_in[29];
    const float* dec_e1 = (const float*)d_in[30];
    const float* out_w  = (const float*)d_in[31];
    const float* out_b  = (const float*)d_in[32];

    char* ws = (char*)d_ws;
    size_t off = 0;
    auto alloc = [&](size_t n) { char* p = ws + off; off += (n + 255) & ~(size_t)255; return p; };

    // transposed hi/lo bf16 weights (~5 MB)
    unsigned short* wt_enc1h = (unsigned short*)alloc((size_t)256 * 128 * 2);
    unsigned short* wt_enc1l = (unsigned short*)alloc((size_t)256 * 128 * 2);
    unsigned short* wt_enc2h = (unsigned short*)alloc((size_t)512 * 256 * 2);
    unsigned short* wt_enc2l = (unsigned short*)alloc((size_t)512 * 256 * 2);
    unsigned short* wt_midh  = (unsigned short*)alloc((size_t)512 * 1024 * 2);
    unsigned short* wt_midl  = (unsigned short*)alloc((size_t)512 * 1024 * 2);
    unsigned short* wt_dec0h = (unsigned short*)alloc((size_t)512 * 768 * 2);
    unsigned short* wt_dec0l = (unsigned short*)alloc((size_t)512 * 768 * 2);
    unsigned short* wt_dec1h = (unsigned short*)alloc((size_t)256 * 640 * 2);
    unsigned short* wt_dec1l = (unsigned short*)alloc((size_t)256 * 640 * 2);

    float* e1    = (float*)alloc((size_t)4 * 512 * 4);
    float* e1q   = (float*)alloc((size_t)4 * 512 * 4);
    unsigned short* tembh = (unsigned short*)alloc((size_t)4 * 512 * 2);
    unsigned short* tembl = (unsigned short*)alloc((size_t)4 * 512 * 2);
    unsigned short* tembq = (unsigned short*)alloc((size_t)4 * 512 * 2);
    float* x0    = (float*)alloc((size_t)RTOT * 6 * 4);

    // CHUNK-SIZED activations (2 chunks of CR=16384 rows).
    // Q: raw bf16; FP: hi/lo bf16 pairs (same bytes as f32); dec1 FP out f32.
    // Peak ~170 MB < 183 known-good.
    unsigned short* skip0q  = (unsigned short*)alloc((size_t)CR * 128 * 2);
    unsigned short* skip1q  = (unsigned short*)alloc((size_t)CR * 256 * 2);
    unsigned short* xAq     = (unsigned short*)alloc((size_t)CR * 512 * 2);
    unsigned short* xBq     = (unsigned short*)alloc((size_t)CR * 512 * 2);
    unsigned short* skip0fh = (unsigned short*)alloc((size_t)CR * 128 * 2);
    unsigned short* skip0fl = (unsigned short*)alloc((size_t)CR * 128 * 2);
    unsigned short* skip1fh = (unsigned short*)alloc((size_t)CR * 256 * 2);
    unsigned short* skip1fl = (unsigned short*)alloc((size_t)CR * 256 * 2);
    unsigned short* xAfh    = (unsigned short*)alloc((size_t)CR * 512 * 2);
    unsigned short* xAfl    = (unsigned short*)alloc((size_t)CR * 512 * 2);
    unsigned short* xBfh    = (unsigned short*)alloc((size_t)CR * 512 * 2);
    unsigned short* xBfl    = (unsigned short*)alloc((size_t)CR * 512 * 2);
    float* xBf32 = (float*)alloc((size_t)CR * 512 * 4);   // dec1 FP out (feeds outproj)

    const int NE = RTOT * NCH;
    double* pd = (double*)xBf32;        // NN scratch (3 MB) aliased onto xBf32;
    int*    pi = (int*)(pd + NE);       // consumed before dec1 ever writes it

    // weight transposes + hi/lo split
    transpose_split_kernel<<<(256 * 128 + 255) / 256, 256, 0, stream>>>(enc_w1, wt_enc1h, wt_enc1l, 128, 256);
    transpose_split_kernel<<<(512 * 256 + 255) / 256, 256, 0, stream>>>(enc_w2, wt_enc2h, wt_enc2l, 256, 512);
    transpose_split_kernel<<<(512 * 1024 + 255) / 256, 256, 0, stream>>>(mid_w, wt_midh, wt_midl, 1024, 512);
    transpose_split_kernel<<<(512 * 768 + 255) / 256, 256, 0, stream>>>(dec_w0, wt_dec0h, wt_dec0l, 768, 512);
    transpose_split_kernel<<<(256 * 640 + 255) / 256, 256, 0, stream>>>(dec_w1, wt_dec1h, wt_dec1l, 640, 256);

    // time embeddings — both precisions in one launch each (z = variant)
    te0_dual<<<dim3(2, 4, 2), 256, 0, stream>>>(tsteps, te_w1, te_b1, e1, e1q);
    te1_dual<<<dim3(2, 4, 2), 256, 0, stream>>>(e1, e1q, te_w2, te_b2, tembh, tembl, tembq);

    // nearest neighbor (exact f64 argmin) + input concat
    nn_partial_kernel<<<dim3(128, NCH), 256, 0, stream>>>(noisy, target, pd, pi);
    nn_merge_kernel<<<128, 256, 0, stream>>>(noisy, target, pd, pi, x0);

    // ---------- both passes concurrent (blockIdx.y), 2 row-chunks ----------
    for (int ch = 0; ch < 2; ch++) {
        const float* x0c = x0 + (size_t)ch * CR * 6;
        const size_t to = (size_t)ch * 2 * 512;   // temb offset: batches 2ch..2ch+1
        float* outc = (float*)d_out + (size_t)ch * CR * 3;

        layer0_dual<<<dim3(CR / 4, 2), 256, 0, stream>>>(
            x0c, enc_w0, enc_b0, enc_g0, enc_e0, skip0q, skip0fh, skip0fl);
        mfma_dual<256><<<dim3(CR / 64, 2), 256, 0, stream>>>(
            skip0q, skip0fh, skip0fl, 128, nullptr, nullptr, nullptr, 0, 0,
            wt_enc1h, wt_enc1l, enc_b1, enc_g1, enc_e1,
            skip1q, skip1fh, skip1fl, nullptr, 128);
        mfma_dual<512><<<dim3(CR / 64, 2), 256, 0, stream>>>(
            skip1q, skip1fh, skip1fl, 256, nullptr, nullptr, nullptr, 0, 0,
            wt_enc2h, wt_enc2l, enc_b2, enc_g2, enc_e2,
            xAq, xAfh, xAfl, nullptr, 256);
        mfma_dual<512><<<dim3(CR / 64, 2), 256, 0, stream>>>(
            xAq, xAfh, xAfl, 512, tembq + to, tembh + to, tembl + to, 512, 13,
            wt_midh, wt_midl, mid_b, mid_g, mid_e,
            xBq, xBfh, xBfl, nullptr, 1024);
        mfma_dual<512><<<dim3(CR / 64, 2), 256, 0, stream>>>(
            xBq, xBfh, xBfl, 512, skip1q, skip1fh, skip1fl, 256, 0,
            wt_dec0h, wt_dec0l, dec_b0, dec_g0, dec_e0,
            xAq, xAfh, xAfl, nullptr, 768);
        mfma_dual<256><<<dim3(CR / 64, 2), 256, 0, stream>>>(
            xAq, xAfh, xAfl, 512, skip0q, skip0fh, skip0fl, 128, 0,
            wt_dec1h, wt_dec1l, dec_b1, dec_g1, dec_e1,
            xBq, nullptr, nullptr, xBf32, 640);
        outproj_fused<<<CR / 4, 256, 0, stream>>>(xBq, xBf32, out_w, out_b, outc);
    }
}

// Round 15
// 1022.317 us; speedup vs baseline: 1.0782x; 1.0625x over previous
//
#include <hip/hip_runtime.h>
#include <stdint.h>

#define RTOT 32768   // B*N
#define CR   16384   // rows per chunk (2 chunks; per-row network => independent)
#define NPTS 8192
#define MPTS 4096
#define NCH 8        // m-chunks per row
#define CHM 512      // m per chunk

typedef float f4v __attribute__((ext_vector_type(4)));
typedef short s8v __attribute__((ext_vector_type(8)));

// direct global->LDS DMA (dwordx4). LDS dest = wave-uniform base + lane*16.
#define GLDS(src, dst) __builtin_amdgcn_global_load_lds( \
    (const __attribute__((address_space(1))) void*)(const void*)(src), \
    (__attribute__((address_space(3))) void*)(void*)(dst), 16, 0, 0)

// round-to-nearest-even bf16, returned as f32 (bf16-valued float)
__device__ __forceinline__ float bq(float f) {
    union { float f; uint32_t i; } u; u.f = f;
    u.i = (u.i + 0x7FFFu + ((u.i >> 16) & 1u)) & 0xFFFF0000u;
    return u.f;
}
__device__ __forceinline__ unsigned short f2bfu(float f) {
    union { float f; uint32_t i; } u; u.f = f;
    return (unsigned short)((u.i + 0x7FFFu + ((u.i >> 16) & 1u)) >> 16);
}
__device__ __forceinline__ float bfu2f(unsigned short s) {
    union { uint32_t i; float f; } u; u.i = ((uint32_t)s) << 16;
    return u.f;
}

// ---------------------------------------------------------------------------
// Weight transpose + hi/lo bf16 split: W (K x N f32) -> Wth/Wtl (N x K bf16).
// ---------------------------------------------------------------------------
__global__ __launch_bounds__(256) void transpose_split_kernel(
    const float* __restrict__ W, unsigned short* __restrict__ Wth,
    unsigned short* __restrict__ Wtl, int K, int N) {
    int i = blockIdx.x * 256 + threadIdx.x;
    if (i < K * N) {
        int n = i / K;
        int k = i % K;
        float w = W[(size_t)k * N + n];
        unsigned short h = f2bfu(w);
        Wth[i] = h;
        Wtl[i] = f2bfu(w - bfu2f(h));
    }
}

// ---------------------------------------------------------------------------
// Time embedding — dual-pass (blockIdx.z: 0 = f32, 1 = Q/bf16-emulated).
// FP output stored as hi/lo bf16 (bit-identical to consumer-side split; R8).
// ---------------------------------------------------------------------------
__global__ __launch_bounds__(256) void te0_dual(
    const float* __restrict__ ts,
    const float* __restrict__ w1, const float* __restrict__ b1,
    float* __restrict__ e1, float* __restrict__ e1q) {
    const bool Qv = (blockIdx.z == 1);
    __shared__ float emb[128];
    const int b = blockIdx.y;
    const int j = blockIdx.x * 256 + threadIdx.x;
    float t = ts[b];
    if (threadIdx.x < 128) {
        int k = threadIdx.x & 63;
        float f = expf((float)k * -0.14619587892025688f);
        float a = t * f;
        float v = (threadIdx.x < 64) ? sinf(a) : cosf(a);
        emb[threadIdx.x] = Qv ? bq(v) : v;
    }
    __syncthreads();
    float acc = 0.f;
    #pragma unroll 8
    for (int k = 0; k < 128; k++) {
        float w = w1[(size_t)k * 512 + j];
        acc += emb[k] * (Qv ? bq(w) : w);
    }
    acc += b1[j];
    if (Qv) {
        float h = bq(acc);
        float sg = bq(1.f / (1.f + expf(-h)));
        e1q[b * 512 + j] = bq(h * sg);
    } else {
        e1[b * 512 + j] = acc / (1.f + expf(-acc));
    }
}

__global__ __launch_bounds__(256) void te1_dual(
    const float* __restrict__ e1, const float* __restrict__ e1q,
    const float* __restrict__ w2, const float* __restrict__ b2,
    unsigned short* __restrict__ tembh, unsigned short* __restrict__ tembl,
    unsigned short* __restrict__ tembq) {
    const bool Qv = (blockIdx.z == 1);
    __shared__ float es[512];
    const int b = blockIdx.y;
    const int j = blockIdx.x * 256 + threadIdx.x;
    const float* src = Qv ? e1q : e1;
    float v0 = src[b * 512 + threadIdx.x];
    float v1 = src[b * 512 + 256 + threadIdx.x];
    es[threadIdx.x] = Qv ? bq(v0) : v0;
    es[256 + threadIdx.x] = Qv ? bq(v1) : v1;
    __syncthreads();
    float acc = 0.f;
    #pragma unroll 8
    for (int k = 0; k < 512; k++) {
        float w = w2[(size_t)k * 512 + j];
        acc += es[k] * (Qv ? bq(w) : w);
    }
    acc += b2[j];
    if (Qv) {
        tembq[b * 512 + j] = f2bfu(acc);   // same bits as bq(acc)
    } else {
        unsigned short h = f2bfu(acc);     // same split the consumer staging did
        tembh[b * 512 + j] = h;
        tembl[b * 512 + j] = f2bfu(acc - bfu2f(h));
    }
}

// ---------------------------------------------------------------------------
// NN search: EXACT f64 argmin (unchanged — established correct).
// ---------------------------------------------------------------------------
__global__ __launch_bounds__(256) void nn_partial_kernel(
    const float* __restrict__ NP, const float* __restrict__ TP,
    double* __restrict__ pd, int* __restrict__ pi) {
    __shared__ float tx[CHM], ty[CHM], tz[CHM];
    __shared__ double t264[CHM];
    const int t = threadIdx.x;
    const int r = blockIdx.x * 256 + t;
    const int b = r >> 13;
    const int ch = blockIdx.y;
    const int m0 = ch * CHM;
    for (int i = t; i < CHM; i += 256) {
        const float* p = TP + ((size_t)b * MPTS + m0 + i) * 3;
        float x = p[0], y = p[1], z = p[2];
        tx[i] = x; ty[i] = y; tz[i] = z;
        t264[i] = (double)x * x + (double)y * y + (double)z * z;
    }
    __syncthreads();
    const float* q = NP + (size_t)r * 3;
    double nx = (double)q[0], ny = (double)q[1], nz = (double)q[2];
    double sn = nx * nx + ny * ny + nz * nz;
    double g1 = 1e300; int j1 = 0;
    for (int m = 0; m < CHM; m++) {
        double d = (sn + t264[m]) - 2.0 * (nx * tx[m] + ny * ty[m] + nz * tz[m]);
        if (d < g1) { g1 = d; j1 = m; }
    }
    size_t o = (size_t)r * NCH + ch;
    pd[o] = g1;
    pi[o] = m0 + j1;
}

__global__ __launch_bounds__(256) void nn_merge_kernel(
    const float* __restrict__ NP, const float* __restrict__ TP,
    const double* __restrict__ pd, const int* __restrict__ pi,
    float* __restrict__ X0) {
    const int r = blockIdx.x * 256 + threadIdx.x;
    double g1 = 1e300; int j1 = 0;
    #pragma unroll
    for (int c = 0; c < NCH; c++) {
        size_t o = (size_t)r * NCH + c;
        double d = pd[o]; int i = pi[o];
        if (d < g1) { g1 = d; j1 = i; }
    }
    const int b = r >> 13;
    const float* tp = TP + ((size_t)b * MPTS + j1) * 3;
    const float* q = NP + (size_t)r * 3;
    float* o = X0 + (size_t)r * 6;
    o[0] = q[0]; o[1] = q[1]; o[2] = q[2];
    o[3] = tp[0]; o[4] = tp[1]; o[5] = tp[2];
}

// ---------------------------------------------------------------------------
// Layer 0 (K=6 -> 128) + LN + SiLU — dual-pass. FP writes hi/lo bf16 (R8,
// bit-identical to f32-store + consumer-side split).
// ---------------------------------------------------------------------------
__global__ __launch_bounds__(256) void layer0_dual(
    const float* __restrict__ X0, const float* __restrict__ W0,
    const float* __restrict__ b0, const float* __restrict__ g0,
    const float* __restrict__ e0,
    unsigned short* __restrict__ OutQ,
    unsigned short* __restrict__ OutFh, unsigned short* __restrict__ OutFl) {
    const bool Qp = (blockIdx.y == 0);
    const int wave = threadIdx.x >> 6;
    const int lane = threadIdx.x & 63;
    const int r = blockIdx.x * 4 + wave;
    float xk[6];
    #pragma unroll
    for (int k = 0; k < 6; k++) {
        float v = X0[(size_t)r * 6 + k];
        xk[k] = Qp ? bq(v) : v;
    }
    const int j0 = lane, j1 = lane + 64;
    float y0 = 0.f, y1 = 0.f;
    #pragma unroll
    for (int k = 0; k < 6; k++) {
        float w0 = W0[k * 128 + j0], w1 = W0[k * 128 + j1];
        y0 += xk[k] * (Qp ? bq(w0) : w0);
        y1 += xk[k] * (Qp ? bq(w1) : w1);
    }
    y0 += b0[j0];
    y1 += b0[j1];
    if (Qp) { y0 = bq(y0); y1 = bq(y1); }
    float s = y0 + y1;
    #pragma unroll
    for (int m = 1; m < 64; m <<= 1) s += __shfl_xor(s, m, 64);
    float mean = s * (1.f / 128.f);
    if (Qp) {
        mean = bq(mean);
        float c0 = bq(y0 - mean), c1 = bq(y1 - mean);
        float q0 = bq(c0 * c0), q1 = bq(c1 * c1);
        float sv = q0 + q1;
        #pragma unroll
        for (int m = 1; m < 64; m <<= 1) sv += __shfl_xor(sv, m, 64);
        float var = bq(sv * (1.f / 128.f));
        float sd = bq(sqrtf(bq(var + 1e-5f)));
        float d0 = bq(c0 / sd), d1 = bq(c1 / sd);
        d0 = bq(bq(d0 * g0[j0]) + e0[j0]);
        d1 = bq(bq(d1 * g0[j1]) + e0[j1]);
        float s0 = bq(1.f / (1.f + expf(-d0)));
        float s1 = bq(1.f / (1.f + expf(-d1)));
        OutQ[(size_t)r * 128 + j0] = f2bfu(d0 * s0);
        OutQ[(size_t)r * 128 + j1] = f2bfu(d1 * s1);
    } else {
        float sq = y0 * y0 + y1 * y1;
        #pragma unroll
        for (int m = 1; m < 64; m <<= 1) sq += __shfl_xor(sq, m, 64);
        float var = sq * (1.f / 128.f) - mean * mean;
        float rstd = rsqrtf(var + 1e-5f);
        float n0 = (y0 - mean) * rstd * g0[j0] + e0[j0];
        float n1 = (y1 - mean) * rstd * g0[j1] + e0[j1];
        float v0 = n0 / (1.f + expf(-n0));
        float v1 = n1 / (1.f + expf(-n1));
        unsigned short h0 = f2bfu(v0), h1 = f2bfu(v1);
        OutFh[(size_t)r * 128 + j0] = h0;
        OutFl[(size_t)r * 128 + j0] = f2bfu(v0 - bfu2f(h0));
        OutFh[(size_t)r * 128 + j1] = h1;
        OutFl[(size_t)r * 128 + j1] = f2bfu(v1 - bfu2f(h1));
    }
}

// ---------------------------------------------------------------------------
// MFMA fused layer — R15: global_load_lds A-staging + source-side swizzle.
// R11/R14 plateau diagnosis: latency-bound at 2 waves/SIMD; A staging
// round-trips 32 VGPR (qa/qb) under the 128 cap (chronic ~12MB epilogue
// spill) and burns ds_write slots. Fix (rule 21 / m97 ladder): LDS tile
// is LINEAR [64 rows][64 k] u16 (no pad — gload_lds requires linear
// dest); lane l stages LDS slot (l&7) of row (l>>3) from GLOBAL source
// slot (l&7)^(l>>3); ds_read applies koff ^= ((c&7)<<3). Content:
// (T^(R&7))^(R&7) = T (verified); bank spread = 8 lanes/quad = the b128
// floor (same as the old padded layout). Producers untouched. Pure data
// movement => bit-exact. Frees ~32 VGPR, removes k-loop ds_writes.
// ---------------------------------------------------------------------------
template <int NOUT, bool FP>
__device__ __forceinline__ void mfma_body(
    const unsigned short* __restrict__ A1a, const unsigned short* __restrict__ A1b, int K1,
    const unsigned short* __restrict__ A2a, const unsigned short* __restrict__ A2b, int K2, int shift,
    const unsigned short* __restrict__ Wth,
    const unsigned short* __restrict__ Wtl,
    const float* __restrict__ bias,
    const float* __restrict__ gamma,
    const float* __restrict__ beta,
    unsigned short* __restrict__ OutQ,
    unsigned short* __restrict__ OutFh, unsigned short* __restrict__ OutFl,
    float* __restrict__ OutF32, int K,
    unsigned short* AhB, unsigned short* AlB, float (*lnS)[16], float (*lnQ)[16]) {
    constexpr int BNW = NOUT / 4;
    constexpr int CT = BNW / 16;
    constexpr int CHK = FP ? 2 : 4;      // B-col tiles per load group

    const int tid = threadIdx.x;
    const int wave = tid >> 6;
    const int lane = tid & 63;
    const int q = lane >> 4;
    const int c = lane & 15;
    const int r0 = blockIdx.x * 64;

    f4v acc[4][CT];
    #pragma unroll
    for (int rt = 0; rt < 4; rt++)
        #pragma unroll
        for (int ct = 0; ct < CT; ct++)
            acc[rt][ct] = (f4v)0.f;

    // ---- direct global->LDS staging with source-side swizzle ----
    // lane l: LDS slot l&7 of tile-row (wave*16 + half*8 + (l>>3));
    // source slot = (l&7) ^ (l>>3)  [tile-row & 7 == l>>3].
    const int rofs = lane >> 3;                  // 0..7
    const int sslot = (lane & 7) ^ rofs;         // swizzled source 16B-slot
    auto stage = [&](int bufIdx, int k0) {
        unsigned short* AhT = AhB + bufIdx * (64 * 64);
        unsigned short* AlT = AlB + bufIdx * (64 * 64);
        #pragma unroll
        for (int half = 0; half < 2; half++) {
            const int rowt = wave * 16 + half * 8 + rofs;   // tile row (this lane)
            const int rg = r0 + rowt;                        // global row
            const unsigned short *sa, *sb;
            size_t base;
            if (k0 < K1) { sa = A1a; sb = A1b; base = (size_t)rg * K1 + k0; }
            else         { sa = A2a; sb = A2b; base = (size_t)(rg >> shift) * K2 + (k0 - K1); }
            // wave-uniform LDS base; HW adds lane*16B = exactly our linear layout
            GLDS(sa + base + sslot * 8, AhT + (wave * 16 + half * 8) * 64);
            if (FP)
                GLDS(sb + base + sslot * 8, AlT + (wave * 16 + half * 8) * 64);
        }
    };

    stage(0, 0);
    __syncthreads();                 // drains gload_lds (vmcnt at barrier)
    int cur = 0;
    for (int k0 = 0; k0 < K; k0 += 64) {
        // issue next tile's DMA into the other buffer (read last iteration,
        // protected by the previous barrier); latency hides under MFMAs
        if (k0 + 64 < K) stage(cur ^ 1, k0 + 64);
        unsigned short* Ah = AhB + cur * (64 * 64);
        unsigned short* Al = AlB + cur * (64 * 64);
        __builtin_amdgcn_s_setprio(1);
        #pragma unroll
        for (int kh = 0; kh < 2; kh++) {
            const int kb = k0 + kh * 32;
            #pragma unroll
            for (int ctb = 0; ctb < CT; ctb += CHK) {
                s8v bh[CHK], bl[CHK];
                #pragma unroll
                for (int j = 0; j < CHK; j++) {
                    int col = wave * BNW + (ctb + j) * 16 + c;
                    bh[j] = *(const s8v*)(Wth + (size_t)col * K + kb + q * 8);
                    if (FP) bl[j] = *(const s8v*)(Wtl + (size_t)col * K + kb + q * 8);
                }
                #pragma unroll
                for (int rt = 0; rt < 4; rt++) {
                    const int koff = ((kh * 32 + q * 8) ^ ((c & 7) << 3));  // swizzled read
                    s8v ah = *(const s8v*)(&Ah[(rt * 16 + c) * 64 + koff]);
                    if (FP) {
                        s8v al = *(const s8v*)(&Al[(rt * 16 + c) * 64 + koff]);
                        #pragma unroll
                        for (int j = 0; j < CHK; j++) {
                            acc[rt][ctb + j] = __builtin_amdgcn_mfma_f32_16x16x32_bf16(ah, bh[j], acc[rt][ctb + j], 0, 0, 0);
                            acc[rt][ctb + j] = __builtin_amdgcn_mfma_f32_16x16x32_bf16(ah, bl[j], acc[rt][ctb + j], 0, 0, 0);
                            acc[rt][ctb + j] = __builtin_amdgcn_mfma_f32_16x16x32_bf16(al, bh[j], acc[rt][ctb + j], 0, 0, 0);
                        }
                    } else {
                        #pragma unroll
                        for (int j = 0; j < CHK; j++)
                            acc[rt][ctb + j] = __builtin_amdgcn_mfma_f32_16x16x32_bf16(ah, bh[j], acc[rt][ctb + j], 0, 0, 0);
                    }
                }
            }
        }
        __builtin_amdgcn_s_setprio(0);
        __syncthreads();             // drains next-tile DMA + guards buf reuse
        cur ^= 1;
    }

    // ---- epilogue (unchanged math per pass; rt 0..3) ----
    float bcol[CT], gcol[CT], ecol[CT];
    #pragma unroll
    for (int ct = 0; ct < CT; ct++) {
        int col = wave * BNW + ct * 16 + c;
        bcol[ct] = bias[col];
        gcol[ct] = gamma[col];
        ecol[ct] = beta[col];
    }
    const float inv = 1.f / (float)NOUT;
    #pragma unroll
    for (int rt = 0; rt < 4; rt++) {
        if (FP) {
            float s[4] = {0.f, 0.f, 0.f, 0.f}, sq[4] = {0.f, 0.f, 0.f, 0.f};
            #pragma unroll
            for (int ct = 0; ct < CT; ct++)
                #pragma unroll
                for (int reg = 0; reg < 4; reg++) {
                    float v = acc[rt][ct][reg] + bcol[ct];
                    acc[rt][ct][reg] = v;
                    s[reg] += v;
                    sq[reg] += v * v;
                }
            #pragma unroll
            for (int m = 1; m < 16; m <<= 1)
                #pragma unroll
                for (int reg = 0; reg < 4; reg++) {
                    s[reg] += __shfl_xor(s[reg], m, 64);
                    sq[reg] += __shfl_xor(sq[reg], m, 64);
                }
            if (c == 0)
                #pragma unroll
                for (int reg = 0; reg < 4; reg++) {
                    lnS[wave][q * 4 + reg] = s[reg];
                    lnQ[wave][q * 4 + reg] = sq[reg];
                }
            __syncthreads();
            #pragma unroll
            for (int reg = 0; reg < 4; reg++) {
                int lr = q * 4 + reg;
                float S = lnS[0][lr] + lnS[1][lr] + lnS[2][lr] + lnS[3][lr];
                float SQ = lnQ[0][lr] + lnQ[1][lr] + lnQ[2][lr] + lnQ[3][lr];
                float mean = S * inv;
                float var = SQ * inv - mean * mean;
                float rstd = rsqrtf(var + 1e-5f);
                size_t rr = (size_t)(r0 + rt * 16 + lr);
                #pragma unroll
                for (int ct = 0; ct < CT; ct++) {
                    float y = (acc[rt][ct][reg] - mean) * rstd * gcol[ct] + ecol[ct];
                    float ys = y / (1.f + expf(-y));
                    size_t idx = rr * NOUT + wave * BNW + ct * 16 + c;
                    if (OutF32) {
                        OutF32[idx] = ys;
                    } else {
                        unsigned short h = f2bfu(ys);
                        OutFh[idx] = h;
                        OutFl[idx] = f2bfu(ys - bfu2f(h));
                    }
                }
            }
            __syncthreads();
        } else {
            float s[4] = {0.f, 0.f, 0.f, 0.f};
            #pragma unroll
            for (int ct = 0; ct < CT; ct++)
                #pragma unroll
                for (int reg = 0; reg < 4; reg++) {
                    float h = bq(acc[rt][ct][reg] + bcol[ct]);
                    acc[rt][ct][reg] = h;
                    s[reg] += h;
                }
            #pragma unroll
            for (int m = 1; m < 16; m <<= 1)
                #pragma unroll
                for (int reg = 0; reg < 4; reg++)
                    s[reg] += __shfl_xor(s[reg], m, 64);
            if (c == 0)
                #pragma unroll
                for (int reg = 0; reg < 4; reg++)
                    lnS[wave][q * 4 + reg] = s[reg];
            __syncthreads();
            float mean[4], sv[4] = {0.f, 0.f, 0.f, 0.f};
            #pragma unroll
            for (int reg = 0; reg < 4; reg++) {
                int lr = q * 4 + reg;
                mean[reg] = bq((lnS[0][lr] + lnS[1][lr] + lnS[2][lr] + lnS[3][lr]) * inv);
            }
            #pragma unroll
            for (int ct = 0; ct < CT; ct++)
                #pragma unroll
                for (int reg = 0; reg < 4; reg++) {
                    float cc = bq(acc[rt][ct][reg] - mean[reg]);
                    acc[rt][ct][reg] = cc;
                    sv[reg] += bq(cc * cc);
                }
            #pragma unroll
            for (int m = 1; m < 16; m <<= 1)
                #pragma unroll
                for (int reg = 0; reg < 4; reg++)
                    sv[reg] += __shfl_xor(sv[reg], m, 64);
            if (c == 0)
                #pragma unroll
                for (int reg = 0; reg < 4; reg++)
                    lnQ[wave][q * 4 + reg] = sv[reg];
            __syncthreads();
            #pragma unroll
            for (int reg = 0; reg < 4; reg++) {
                int lr = q * 4 + reg;
                float var = bq((lnQ[0][lr] + lnQ[1][lr] + lnQ[2][lr] + lnQ[3][lr]) * inv);
                float sd = bq(sqrtf(bq(var + 1e-5f)));
                size_t rr = (size_t)(r0 + rt * 16 + lr);
                #pragma unroll
                for (int ct = 0; ct < CT; ct++) {
                    float d = bq(acc[rt][ct][reg] / sd);
                    d = bq(bq(d * gcol[ct]) + ecol[ct]);
                    float sg = bq(1.f / (1.f + expf(-d)));
                    OutQ[rr * NOUT + wave * BNW + ct * 16 + c] = f2bfu(d * sg);
                }
            }
            __syncthreads();
        }
    }
}

template <int NOUT>
__global__ __launch_bounds__(256, 2) void mfma_dual(
    const unsigned short* __restrict__ A1q,
    const unsigned short* __restrict__ A1h, const unsigned short* __restrict__ A1l, int K1,
    const unsigned short* __restrict__ A2q,
    const unsigned short* __restrict__ A2h, const unsigned short* __restrict__ A2l, int K2, int shift,
    const unsigned short* __restrict__ Wth,
    const unsigned short* __restrict__ Wtl,
    const float* __restrict__ bias,
    const float* __restrict__ gamma,
    const float* __restrict__ beta,
    unsigned short* __restrict__ OutQ,
    unsigned short* __restrict__ OutFh, unsigned short* __restrict__ OutFl,
    float* __restrict__ OutF32, int K) {
    __shared__ __align__(16) unsigned short Ah[2][64 * 64];   // dbuf, linear
    __shared__ __align__(16) unsigned short Al[2][64 * 64];
    __shared__ float lnS[4][16];
    __shared__ float lnQ[4][16];
    if (blockIdx.y == 0)
        mfma_body<NOUT, false>(A1q, nullptr, K1, A2q, nullptr, K2, shift, Wth, Wtl,
                               bias, gamma, beta, OutQ, nullptr, nullptr, nullptr, K,
                               &Ah[0][0], &Al[0][0], lnS, lnQ);
    else
        mfma_body<NOUT, true>(A1h, A1l, K1, A2h, A2l, K2, shift, Wth, Wtl,
                              bias, gamma, beta, OutQ, OutFh, OutFl, OutF32, K,
                              &Ah[0][0], &Al[0][0], lnS, lnQ);
}

// ---------------------------------------------------------------------------
// Output projection — fused Q + f32 dot, blends 0.2/0.8 exactly as before.
// ---------------------------------------------------------------------------
__global__ __launch_bounds__(256) void outproj_fused(
    const unsigned short* __restrict__ Xq, const float* __restrict__ Xf,
    const float* __restrict__ W, const float* __restrict__ bO,
    float* __restrict__ Out) {
    const int wave = threadIdx.x >> 6;
    const int lane = threadIdx.x & 63;
    const int r = blockIdx.x * 4 + wave;
    float q0 = 0.f, q1 = 0.f, q2 = 0.f;
    float f0 = 0.f, f1 = 0.f, f2 = 0.f;
    #pragma unroll
    for (int i = 0; i < 4; i++) {
        int k = lane + i * 64;
        float xq = bfu2f(Xq[(size_t)r * 256 + k]);
        float xf = Xf[(size_t)r * 256 + k];
        float w0 = W[k * 3 + 0], w1 = W[k * 3 + 1], w2 = W[k * 3 + 2];
        q0 += xq * bq(w0); q1 += xq * bq(w1); q2 += xq * bq(w2);
        f0 += xf * w0;     f1 += xf * w1;     f2 += xf * w2;
    }
    #pragma unroll
    for (int m = 1; m < 64; m <<= 1) {
        q0 += __shfl_xor(q0, m, 64);
        q1 += __shfl_xor(q1, m, 64);
        q2 += __shfl_xor(q2, m, 64);
        f0 += __shfl_xor(f0, m, 64);
        f1 += __shfl_xor(f1, m, 64);
        f2 += __shfl_xor(f2, m, 64);
    }
    if (lane == 0) {
        float a0 = bq(q0 + bO[0]);
        float a1 = bq(q1 + bO[1]);
        float a2 = bq(q2 + bO[2]);
        Out[(size_t)r * 3 + 0] = 0.2f * (f0 + bO[0]) + 0.8f * a0;
        Out[(size_t)r * 3 + 1] = 0.2f * (f1 + bO[1]) + 0.8f * a1;
        Out[(size_t)r * 3 + 2] = 0.2f * (f2 + bO[2]) + 0.8f * a2;
    }
}

// ---------------------------------------------------------------------------
extern "C" void kernel_launch(void* const* d_in, const int* in_sizes, int n_in,
                              void* d_out, int out_size, void* d_ws, size_t ws_size,
                              hipStream_t stream) {
    (void)in_sizes; (void)n_in; (void)out_size; (void)ws_size;
    const float* noisy  = (const float*)d_in[0];
    const float* target = (const float*)d_in[1];
    const float* tsteps = (const float*)d_in[2];
    const float* te_w1  = (const float*)d_in[3];
    const float* te_b1  = (const float*)d_in[4];
    const float* te_w2  = (const float*)d_in[5];
    const float* te_b2  = (const float*)d_in[6];
    const float* enc_w0 = (const float*)d_in[7];
    const float* enc_b0 = (const float*)d_in[8];
    const float* enc_g0 = (const float*)d_in[9];
    const float* enc_e0 = (const float*)d_in[10];
    const float* enc_w1 = (const float*)d_in[11];
    const float* enc_b1 = (const float*)d_in[12];
    const float* enc_g1 = (const float*)d_in[13];
    const float* enc_e1 = (const float*)d_in[14];
    const float* enc_w2 = (const float*)d_in[15];
    const float* enc_b2 = (const float*)d_in[16];
    const float* enc_g2 = (const float*)d_in[17];
    const float* enc_e2 = (const float*)d_in[18];
    const float* mid_w  = (const float*)d_in[19];
    const float* mid_b  = (const float*)d_in[20];
    const float* mid_g  = (const float*)d_in[21];
    const float* mid_e  = (const float*)d_in[22];
    const float* dec_w0 = (const float*)d_in[23];
    const float* dec_b0 = (const float*)d_in[24];
    const float* dec_g0 = (const float*)d_in[25];
    const float* dec_e0 = (const float*)d_in[26];
    const float* dec_w1 = (const float*)d_in[27];
    const float* dec_b1 = (const float*)d_in[28];
    const float* dec_g1 = (const float*)d_in[29];
    const float* dec_e1 = (const float*)d_in[30];
    const float* out_w  = (const float*)d_in[31];
    const float* out_b  = (const float*)d_in[32];

    char* ws = (char*)d_ws;
    size_t off = 0;
    auto alloc = [&](size_t n) { char* p = ws + off; off += (n + 255) & ~(size_t)255; return p; };

    // transposed hi/lo bf16 weights (~5 MB)
    unsigned short* wt_enc1h = (unsigned short*)alloc((size_t)256 * 128 * 2);
    unsigned short* wt_enc1l = (unsigned short*)alloc((size_t)256 * 128 * 2);
    unsigned short* wt_enc2h = (unsigned short*)alloc((size_t)512 * 256 * 2);
    unsigned short* wt_enc2l = (unsigned short*)alloc((size_t)512 * 256 * 2);
    unsigned short* wt_midh  = (unsigned short*)alloc((size_t)512 * 1024 * 2);
    unsigned short* wt_midl  = (unsigned short*)alloc((size_t)512 * 1024 * 2);
    unsigned short* wt_dec0h = (unsigned short*)alloc((size_t)512 * 768 * 2);
    unsigned short* wt_dec0l = (unsigned short*)alloc((size_t)512 * 768 * 2);
    unsigned short* wt_dec1h = (unsigned short*)alloc((size_t)256 * 640 * 2);
    unsigned short* wt_dec1l = (unsigned short*)alloc((size_t)256 * 640 * 2);

    float* e1    = (float*)alloc((size_t)4 * 512 * 4);
    float* e1q   = (float*)alloc((size_t)4 * 512 * 4);
    unsigned short* tembh = (unsigned short*)alloc((size_t)4 * 512 * 2);
    unsigned short* tembl = (unsigned short*)alloc((size_t)4 * 512 * 2);
    unsigned short* tembq = (unsigned short*)alloc((size_t)4 * 512 * 2);
    float* x0    = (float*)alloc((size_t)RTOT * 6 * 4);

    // CHUNK-SIZED activations (2 chunks of CR=16384 rows). Peak ~170 MB.
    unsigned short* skip0q  = (unsigned short*)alloc((size_t)CR * 128 * 2);
    unsigned short* skip1q  = (unsigned short*)alloc((size_t)CR * 256 * 2);
    unsigned short* xAq     = (unsigned short*)alloc((size_t)CR * 512 * 2);
    unsigned short* xBq     = (unsigned short*)alloc((size_t)CR * 512 * 2);
    unsigned short* skip0fh = (unsigned short*)alloc((size_t)CR * 128 * 2);
    unsigned short* skip0fl = (unsigned short*)alloc((size_t)CR * 128 * 2);
    unsigned short* skip1fh = (unsigned short*)alloc((size_t)CR * 256 * 2);
    unsigned short* skip1fl = (unsigned short*)alloc((size_t)CR * 256 * 2);
    unsigned short* xAfh    = (unsigned short*)alloc((size_t)CR * 512 * 2);
    unsigned short* xAfl    = (unsigned short*)alloc((size_t)CR * 512 * 2);
    unsigned short* xBfh    = (unsigned short*)alloc((size_t)CR * 512 * 2);
    unsigned short* xBfl    = (unsigned short*)alloc((size_t)CR * 512 * 2);
    float* xBf32 = (float*)alloc((size_t)CR * 512 * 4);   // dec1 FP out (feeds outproj)

    const int NE = RTOT * NCH;
    double* pd = (double*)xBf32;        // NN scratch (3 MB) aliased onto xBf32;
    int*    pi = (int*)(pd + NE);       // consumed before dec1 ever writes it

    // weight transposes + hi/lo split
    transpose_split_kernel<<<(256 * 128 + 255) / 256, 256, 0, stream>>>(enc_w1, wt_enc1h, wt_enc1l, 128, 256);
    transpose_split_kernel<<<(512 * 256 + 255) / 256, 256, 0, stream>>>(enc_w2, wt_enc2h, wt_enc2l, 256, 512);
    transpose_split_kernel<<<(512 * 1024 + 255) / 256, 256, 0, stream>>>(mid_w, wt_midh, wt_midl, 1024, 512);
    transpose_split_kernel<<<(512 * 768 + 255) / 256, 256, 0, stream>>>(dec_w0, wt_dec0h, wt_dec0l, 768, 512);
    transpose_split_kernel<<<(256 * 640 + 255) / 256, 256, 0, stream>>>(dec_w1, wt_dec1h, wt_dec1l, 640, 256);

    // time embeddings — both precisions in one launch each (z = variant)
    te0_dual<<<dim3(2, 4, 2), 256, 0, stream>>>(tsteps, te_w1, te_b1, e1, e1q);
    te1_dual<<<dim3(2, 4, 2), 256, 0, stream>>>(e1, e1q, te_w2, te_b2, tembh, tembl, tembq);

    // nearest neighbor (exact f64 argmin) + input concat
    nn_partial_kernel<<<dim3(128, NCH), 256, 0, stream>>>(noisy, target, pd, pi);
    nn_merge_kernel<<<128, 256, 0, stream>>>(noisy, target, pd, pi, x0);

    // ---------- both passes concurrent (blockIdx.y), 2 row-chunks ----------
    for (int ch = 0; ch < 2; ch++) {
        const float* x0c = x0 + (size_t)ch * CR * 6;
        const size_t to = (size_t)ch * 2 * 512;   // temb offset: batches 2ch..2ch+1
        float* outc = (float*)d_out + (size_t)ch * CR * 3;

        layer0_dual<<<dim3(CR / 4, 2), 256, 0, stream>>>(
            x0c, enc_w0, enc_b0, enc_g0, enc_e0, skip0q, skip0fh, skip0fl);
        mfma_dual<256><<<dim3(CR / 64, 2), 256, 0, stream>>>(
            skip0q, skip0fh, skip0fl, 128, nullptr, nullptr, nullptr, 0, 0,
            wt_enc1h, wt_enc1l, enc_b1, enc_g1, enc_e1,
            skip1q, skip1fh, skip1fl, nullptr, 128);
        mfma_dual<512><<<dim3(CR / 64, 2), 256, 0, stream>>>(
            skip1q, skip1fh, skip1fl, 256, nullptr, nullptr, nullptr, 0, 0,
            wt_enc2h, wt_enc2l, enc_b2, enc_g2, enc_e2,
            xAq, xAfh, xAfl, nullptr, 256);
        mfma_dual<512><<<dim3(CR / 64, 2), 256, 0, stream>>>(
            xAq, xAfh, xAfl, 512, tembq + to, tembh + to, tembl + to, 512, 13,
            wt_midh, wt_midl, mid_b, mid_g, mid_e,
            xBq, xBfh, xBfl, nullptr, 1024);
        mfma_dual<512><<<dim3(CR / 64, 2), 256, 0, stream>>>(
            xBq, xBfh, xBfl, 512, skip1q, skip1fh, skip1fl, 256, 0,
            wt_dec0h, wt_dec0l, dec_b0, dec_g0, dec_e0,
            xAq, xAfh, xAfl, nullptr, 768);
        mfma_dual<256><<<dim3(CR / 64, 2), 256, 0, stream>>>(
            xAq, xAfh, xAfl, 512, skip0q, skip0fh, skip0fl, 128, 0,
            wt_dec1h, wt_dec1l, dec_b1, dec_g1, dec_e1,
            xBq, nullptr, nullptr, xBf32, 640);
        outproj_fused<<<CR / 4, 256, 0, stream>>>(xBq, xBf32, out_w, out_b, outc);
    }
}